// Round 4
// baseline (208.080 us; speedup 1.0000x reference)
//
#include <hip/hip_runtime.h>

// CausalSelfAttention: B=2, S=2048, D=1024, H=16, Hd=64
// qkv = x@w_qkv+b ; per-head causal softmax(QK^T/8)V ; out = ao@w_proj+b
//
// Fragment layouts (gfx950, HW-verified per guide):
//   16x16x32: A[m=lane&15][k=(lane>>4)*8+j]; B[k][n=lane&15]; C/D col=lane&15,
//             row=(lane>>4)*4+reg
//   32x32x16: A[m=lane&31][k=(lane>>5)*8+j]; B[k=(lane>>5)*8+j][n=lane&31];
//             C/D col=lane&31, row=(reg&3)+8*(reg>>2)+4*(lane>>5)  [m74/m101]
//
// R13: GEMM mainloop rebuilt on the attn-proven staging structure:
// triple-buffered LDS, prefetch distance 2, ONE barrier/K-step with counted
// s_waitcnt vmcnt(LOADS) (never 0 in-loop; dummy re-stage keeps the ledger
// exact; vmcnt(0) once after the loop). Both-sides XOR swizzle (16B slot
// c ^= (row>>1)&3): pre-swizzled GLOBAL source + linear LDS dest (m104) +
// swizzled read -> 2-way banks (free) instead of 8-way.
// Attention: R3-passing body (swapped 32x32 QK^T, in-register P via cvt_pk +
// permlane32_swap, ones-column MFMA row-sums, triple-buffer vmcnt(4) pipeline,
// XCD remap pinning 4 (b,h) per XCD, complement-paired qg).

typedef float f32x4 __attribute__((ext_vector_type(4)));
typedef float f32x16 __attribute__((ext_vector_type(16)));
typedef short bf16x8 __attribute__((ext_vector_type(8)));

#if __has_builtin(__builtin_amdgcn_exp2f)
#define EXP2(x) __builtin_amdgcn_exp2f(x)
#else
#define EXP2(x) exp2f(x)
#endif

__device__ __forceinline__ unsigned short f2bf(float f) {
  union { float f; unsigned u; } v; v.f = f;
  unsigned u = v.u + 0x7fffu + ((v.u >> 16) & 1u);   // RNE
  return (unsigned short)(u >> 16);
}

// async global->LDS, 16 bytes per lane; lds base must be wave-uniform,
// lane l's data lands at lds_base + l*16 bytes (m104/m108 semantics).
__device__ __forceinline__ void async_load16(const void* g, void* lds) {
  __builtin_amdgcn_global_load_lds(
      (const __attribute__((address_space(1))) void*)g,
      (__attribute__((address_space(3))) void*)lds, 16, 0, 0);
}

// ---------------- prep: fp32 -> bf16 elementwise ----------------
__global__ void f32_to_bf16_kernel(const float* __restrict__ in,
                                   unsigned short* __restrict__ out, int n) {
  int i = (blockIdx.x * 256 + threadIdx.x) * 4;
  if (i < n) {
    float4 f = *(const float4*)(in + i);
    ushort4 o;
    o.x = f2bf(f.x); o.y = f2bf(f.y); o.z = f2bf(f.z); o.w = f2bf(f.w);
    *(ushort4*)(out + i) = o;
  }
}

// ---------------- prep: fp32 [K][N] -> bf16 [N][K] ----------------
__global__ void transpose_f32_bf16_kernel(const float* __restrict__ in,
                                          unsigned short* __restrict__ out,
                                          int K, int N) {
  __shared__ float tile[32][33];
  int n0 = blockIdx.x * 32, k0 = blockIdx.y * 32;
  int tx = threadIdx.x, ty = threadIdx.y;  // block (32,8)
#pragma unroll
  for (int i = ty; i < 32; i += 8)
    tile[i][tx] = in[(size_t)(k0 + i) * N + (n0 + tx)];
  __syncthreads();
#pragma unroll
  for (int i = ty; i < 32; i += 8)
    out[(size_t)(n0 + i) * K + (k0 + tx)] = f2bf(tile[tx][i]);
}

// ---------------- shared GEMM mainloop (triple-buffer, counted vmcnt) -----
// As: 3 buffers of [AROWS][32] ushort; Bs: 3 buffers of [BROWS][32].
// Per K-step (per wave): LOADS = AINST+BINST global_load_lds_dwordx4.
// Ledger: stage(t),stage(t+1) in flight at loop top -> wait vmcnt(LOADS)
// completes stage(t), leaves stage(t+1) flying; stage(t+2) re-arms.
// 16B-slot swizzle c^=(row>>1)&3 on global src + read side (linear LDS dest).
template <int MI, int NI>
__device__ __forceinline__ void gemm_mainloop(
    const unsigned short* __restrict__ A,   // [M][K] row-major bf16
    const unsigned short* __restrict__ BT,  // [N][K] row-major bf16
    int K, int mBlk, int nBlk,
    unsigned short* As, unsigned short* Bs,
    f32x4 (&acc)[MI][NI], int lane, int wave)
{
  const int l16 = lane & 15, quad = lane >> 4;
  const int mW = (wave >> 1) * MI * 16;
  const int nW = (wave & 1) * NI * 16;
  constexpr int AROWS = 2 * MI * 16;
  constexpr int BROWS = 2 * NI * 16;
  constexpr int AINST = AROWS / 64;
  constexpr int BINST = BROWS / 64;
  constexpr int LOADS = AINST + BINST;
  constexpr int ABUF = AROWS * 32;
  constexpr int BBUF = BROWS * 32;
  const int rl = lane >> 2;           // row within a 16-row instruction
  const int cl = lane & 3;            // 16B slot within the 64B row
  const int NT = K / 32;

  auto stage = [&](int t, int buf) {
#pragma unroll
    for (int i = 0; i < AINST; ++i) {
      const int rbase = wave * (AROWS / 4) + i * 16;
      const int row = rbase + rl;
      const int cg = cl ^ ((row >> 1) & 3);       // pre-swizzled global chunk
      async_load16(A + (size_t)(mBlk + row) * K + t * 32 + cg * 8,
                   &As[buf * ABUF + rbase * 32]);
    }
#pragma unroll
    for (int i = 0; i < BINST; ++i) {
      const int rbase = wave * (BROWS / 4) + i * 16;
      const int row = rbase + rl;
      const int cg = cl ^ ((row >> 1) & 3);
      async_load16(BT + (size_t)(nBlk + row) * K + t * 32 + cg * 8,
                   &Bs[buf * BBUF + rbase * 32]);
    }
  };

  stage(0, 0);
  stage(1, 1);
  for (int t = 0; t < NT; ++t) {
    asm volatile("s_waitcnt vmcnt(%0)\n\ts_barrier" :: "n"(LOADS) : "memory");
    const int tn = (t + 2 < NT) ? t + 2 : NT - 1;  // dummy re-stage at the end
    stage(tn, (t + 2) % 3);                        // ledger stays exact

    const unsigned short* Ab = As + (t % 3) * ABUF;
    const unsigned short* Bb = Bs + (t % 3) * BBUF;
    bf16x8 af[MI], bf[NI];
#pragma unroll
    for (int i = 0; i < MI; ++i) {
      const int row = mW + i * 16 + l16;
      af[i] = *(const bf16x8*)&Ab[row * 32 + (quad ^ ((row >> 1) & 3)) * 8];
    }
#pragma unroll
    for (int j = 0; j < NI; ++j) {
      const int row = nW + j * 16 + l16;
      bf[j] = *(const bf16x8*)&Bb[row * 32 + (quad ^ ((row >> 1) & 3)) * 8];
    }
    __builtin_amdgcn_s_setprio(1);
#pragma unroll
    for (int i = 0; i < MI; ++i)
#pragma unroll
      for (int j = 0; j < NI; ++j)
        acc[i][j] = __builtin_amdgcn_mfma_f32_16x16x32_bf16(af[i], bf[j], acc[i][j], 0, 0, 0);
    __builtin_amdgcn_s_setprio(0);
  }
  // drain the dummy stages so no DMA outlives this block's LDS allocation
  asm volatile("s_waitcnt vmcnt(0)" ::: "memory");
}

// ---------------- QKV GEMM: [4096,1024]x[1024,3072] + bias ----------------
// Q plane: [2][16][2048][64] pre-scaled by 0.125*log2(e) (softmax in exp2 domain)
// K plane: [2][16][2048][64]
// V plane: TRANSPOSED [2][16][64][2048]
__global__ __launch_bounds__(256) void qkv_gemm_kernel(
    const unsigned short* __restrict__ A,   // x bf16 [4096][1024]
    const unsigned short* __restrict__ WT,  // w_qkv^T bf16 [3072][1024]
    const float* __restrict__ bias,         // [3072]
    unsigned short* __restrict__ QKV)
{
  __shared__ unsigned short As[3 * 128 * 32];   // 24 KB
  __shared__ unsigned short Bs[3 * 128 * 32];   // 24 KB
  const int lane = threadIdx.x & 63;
  const int wave = threadIdx.x >> 6;
  const int l16 = lane & 15, quad = lane >> 4;

  f32x4 acc[4][4];
  const f32x4 z4 = {0.f, 0.f, 0.f, 0.f};
#pragma unroll
  for (int i = 0; i < 4; ++i)
#pragma unroll
    for (int j = 0; j < 4; ++j) acc[i][j] = z4;

  gemm_mainloop<4, 4>(A, WT, 1024, blockIdx.x * 128, blockIdx.y * 128,
                      As, Bs, acc, lane, wave);

  const int m0 = blockIdx.x * 128 + (wave >> 1) * 64;
  const int n0 = blockIdx.y * 128 + (wave & 1) * 64;
  const int whichW = n0 >> 10;          // uniform per wave (64 | 1024)
  const int bb = m0 >> 11;              // uniform per wave (64 | 2048)
  const int sBase = (m0 & 2047);
  const size_t planeE = (size_t)2 * 16 * 2048 * 64;

  if (whichW == 2) {                    // V -> transposed store
    unsigned short* Vb = QKV + 2 * planeE;
#pragma unroll
    for (int j = 0; j < 4; ++j) {
      const int rem = (n0 & 1023) + j * 16 + l16;
      const int hh = rem >> 6, hd = rem & 63;
      const float bv = bias[n0 + j * 16 + l16];
      unsigned short* col = Vb + (((size_t)bb * 16 + hh) * 64 + hd) * 2048;
#pragma unroll
      for (int i = 0; i < 4; ++i) {
        unsigned short pk[4];
#pragma unroll
        for (int r = 0; r < 4; ++r) pk[r] = f2bf(acc[i][j][r] + bv);
        *(ushort4*)&col[sBase + i * 16 + quad * 4] = *(ushort4*)pk;
      }
    }
  } else {
    // Q: fold 1/sqrt(Hd) AND log2(e) -> scores come out in log2 domain
    const float scale = (whichW == 0) ? 0.18033688011112042f : 1.0f;
#pragma unroll
    for (int j = 0; j < 4; ++j) {
      const int n = n0 + j * 16 + l16;
      const float bv = bias[n];
      const int rem = n & 1023;
      const int hh = rem >> 6, hd = rem & 63;
      unsigned short* pl = QKV + (size_t)whichW * planeE +
                           (((size_t)bb * 16 + hh) * 2048) * 64 + hd;
#pragma unroll
      for (int r = 0; r < 4; ++r) {
        const int s = sBase + (quad * 4 + r);
#pragma unroll
        for (int i = 0; i < 4; ++i)
          pl[(size_t)(s + i * 16) * 64] = f2bf((acc[i][j][r] + bv) * scale);
      }
    }
  }
}

// ---------------- flash attention (swapped 32x32, in-register P) ----------
// Block = 4 waves x 32 queries = 128 queries of one (b,h). Linear grid 512:
//   xcd = lin&7, slot = lin>>3; col = xcd*4 + (slot>>4); b = col>>4, h = col&15
//   qg = slot<32 ? slot&15 : 15-(slot&15)
// -> each XCD sees only 4 (b,h) columns (2MB K/V, L2-resident); CU c within
// an XCD gets slots c and c+32 -> qg complement pair (balanced work).
// Body is the R1-proven schedule: per tile QK -> softmax -> PV, 3 buffers.
__global__ __launch_bounds__(256, 2) void attn_kernel(
    const unsigned short* __restrict__ QKV,
    unsigned short* __restrict__ AO)         // [2][2048][1024] bf16
{
  __shared__ __align__(16) unsigned short Ks[3 * 64 * 64];  // 24 KB
  __shared__ __align__(16) unsigned short Vs[3 * 64 * 64];  // 24 KB
  const int lane = threadIdx.x & 63;
  const int wave = threadIdx.x >> 6;
  const int l31 = lane & 31;
  const int hi  = lane >> 5;

  const int lin  = blockIdx.x;
  const int xcd  = lin & 7;
  const int slot = lin >> 3;                 // 0..63
  const int col  = xcd * 4 + (slot >> 4);    // 0..31
  const int b = col >> 4, h = col & 15;
  const int qg = (slot < 32) ? (slot & 15) : (15 - (slot & 15));
  const int qw = qg * 128 + wave * 32;       // this wave's first query

  const size_t planeE = (size_t)2 * 16 * 2048 * 64;
  const size_t bhS = ((size_t)b * 16 + h) * (size_t)(2048 * 64);
  const unsigned short* Q   = QKV + bhS;                 // [2048][64], pre-scaled
  const unsigned short* Kg  = QKV + planeE + bhS;        // [2048][64]
  const unsigned short* VTg = QKV + 2 * planeE + bhS;    // [64][2048]

  // Q B-frags: B[k=hd][n=query=l31]; frag t covers hd t*16 + hi*8 .. +7
  bf16x8 qf_[4];
#pragma unroll
  for (int t = 0; t < 4; ++t)
    qf_[t] = *(const bf16x8*)(Q + (size_t)(qw + l31) * 64 + t * 16 + hi * 8);

  bf16x8 onesf;                               // B-frag of bf16(1.0)
#pragma unroll
  for (int i = 0; i < 8; ++i) onesf[i] = (short)0x3F80;

  f32x16 O[2], Osum;
#pragma unroll
  for (int r = 0; r < 16; ++r) { O[0][r] = 0.f; O[1][r] = 0.f; Osum[r] = 0.f; }

  // DMA role: waves 0,1 stage K; waves 2,3 stage V. 4 instr/wave, 1KB each.
  const int tbase = (wave & 1) * 4;
  const bool doV = wave >= 2;

  auto stage = [&](int tileIdx, int bufIdx) {
    const int kt = tileIdx * 64;
    unsigned short* Kb = Ks + bufIdx * 4096;
    unsigned short* Vb = Vs + bufIdx * 4096;
#pragma unroll
    for (int i = 0; i < 4; ++i) {
      const int t = tbase + i;
      const int s = t * 64 + lane;           // 16B slot this lane fills
      const int row = s >> 3;
      const int c = (s & 7) ^ (row & 7);     // un-swizzle: which global 16B
      if (doV)
        async_load16(VTg + (size_t)row * 2048 + kt + c * 8, Vb + t * 512);
      else
        async_load16(Kg + (size_t)(kt + row) * 64 + c * 8, Kb + t * 512);
    }
  };

  const int nt = qg * 2 + 2;                 // staged tiles (covers wave 3)
  stage(0, 0);
  stage(1, 1);
  for (int ti = 0; ti < nt; ++ti) {
    // wait for stage(ti) (leaves the 4 newest = stage(ti+1) in flight),
    // then barrier. NO vmcnt(0) drain — the AITER-style pipeline.
    asm volatile("s_waitcnt vmcnt(4)\n\ts_barrier" ::: "memory");
    const int tn = (ti + 2 < nt) ? ti + 2 : nt - 1;  // dummy re-stage at the end
    stage(tn, (ti + 2) % 3);                 // keeps 4 in flight per wave, always
    const int kt = ti * 64;
    const unsigned short* Kb = Ks + (ti % 3) * 4096;
    const unsigned short* Vb = Vs + (ti % 3) * 4096;

    if (kt <= qw + 31) {
      const bool dmask = (kt + 63 > qw);
#pragma unroll
      for (int kg = 0; kg < 2; ++kg) {
        // K A-frags: A[m=key=l31(+kg*32)][k=hd chunk], swizzled LDS
        const int krow = kg * 32 + l31;
        const int ks7 = krow & 7;
        bf16x8 ka[4];
#pragma unroll
        for (int t = 0; t < 4; ++t)
          ka[t] = *(const bf16x8*)&Kb[(krow * 8 + ((t * 2 + hi) ^ ks7)) * 8];

        f32x16 sc;
#pragma unroll
        for (int r = 0; r < 16; ++r) sc[r] = 0.f;
        __builtin_amdgcn_s_setprio(1);
#pragma unroll
        for (int t = 0; t < 4; ++t)
          sc = __builtin_amdgcn_mfma_f32_32x32x16_bf16(ka[t], qf_[t], sc, 0, 0, 0);
        __builtin_amdgcn_s_setprio(0);

        // softmax term, fully in-register
        float p[16];
#pragma unroll
        for (int r = 0; r < 16; ++r) {
          float v = sc[r];
          if (dmask) {
            const int key = kt + kg * 32 + (r & 3) + 8 * (r >> 2) + 4 * hi;
            if (key > qw + l31) v = -INFINITY;
          }
          p[r] = EXP2(v);                    // native v_exp_f32
        }
        // pack pairs (keys ascend 2-at-a-time within each lane half)
        unsigned c8[8];
#pragma unroll
        for (int i = 0; i < 8; ++i)
          asm("v_cvt_pk_bf16_f32 %0, %1, %2"
              : "=v"(c8[i]) : "v"(p[2 * i]), "v"(p[2 * i + 1]));

#pragma unroll
        for (int half = 0; half < 2; ++half) {
          // assemble PV A-frag for 16-key chunk kc = kg*2+half:
          // lane half 0 needs keys kc*16+0..7, half 1 needs +8..15.
          unsigned a0 = c8[4 * half + 0], a1 = c8[4 * half + 1];
          unsigned a2 = c8[4 * half + 2], a3 = c8[4 * half + 3];
          asm("v_permlane32_swap_b32 %0, %1" : "+v"(a0), "+v"(a2));
          asm("v_permlane32_swap_b32 %0, %1" : "+v"(a1), "+v"(a3));
          union { unsigned u[4]; bf16x8 v; } pa;
          pa.u[0] = a0; pa.u[1] = a1; pa.u[2] = a2; pa.u[3] = a3;
          const int kc = kg * 2 + half;

          __builtin_amdgcn_s_setprio(1);
          // row-sum on the matrix pipe; lands in O's row layout
          Osum = __builtin_amdgcn_mfma_f32_32x32x16_bf16(pa.v, onesf, Osum, 0, 0, 0);
#pragma unroll
          for (int g = 0; g < 2; ++g) {
            const int vrow = g * 32 + l31;   // hd row of V^T
            bf16x8 vb = *(const bf16x8*)&Vb[(vrow * 8 + ((kc * 2 + hi) ^ (vrow & 7))) * 8];
            O[g] = __builtin_amdgcn_mfma_f32_32x32x16_bf16(pa.v, vb, O[g], 0, 0, 0);
          }
          __builtin_amdgcn_s_setprio(0);
        }
      }
    }
  }

  // epilogue: normalize by Osum (already per-row, replicated across lanes)
  unsigned short* base = AO + ((size_t)b * 2048 + qw) * 1024 + h * 64 + l31;
#pragma unroll
  for (int r = 0; r < 16; ++r) {
    const float inv = 1.0f / Osum[r];
    const int row = (r & 3) + 8 * (r >> 2) + 4 * hi;
#pragma unroll
    for (int g = 0; g < 2; ++g)
      base[(size_t)row * 1024 + g * 32] = f2bf(O[g][r] * inv);
  }
}

// ---------------- proj GEMM: [4096,1024]x[1024,1024] + bias -> fp32 out ----------------
// 64x128 block tile -> grid 64x8 = 512 blocks (2/CU)
__global__ __launch_bounds__(256) void proj_gemm_kernel(
    const unsigned short* __restrict__ A,   // AO bf16 [4096][1024]
    const unsigned short* __restrict__ WT,  // w_proj^T bf16 [1024][1024]
    const float* __restrict__ bias,         // [1024]
    float* __restrict__ out)                // [4096][1024] fp32
{
  __shared__ unsigned short As[3 * 64 * 32];    // 12 KB
  __shared__ unsigned short Bs[3 * 128 * 32];   // 24 KB
  const int lane = threadIdx.x & 63;
  const int wave = threadIdx.x >> 6;
  const int l16 = lane & 15, quad = lane >> 4;

  f32x4 acc[2][4];
  const f32x4 z4 = {0.f, 0.f, 0.f, 0.f};
#pragma unroll
  for (int i = 0; i < 2; ++i)
#pragma unroll
    for (int j = 0; j < 4; ++j) acc[i][j] = z4;

  gemm_mainloop<2, 4>(A, WT, 1024, blockIdx.x * 64, blockIdx.y * 128,
                      As, Bs, acc, lane, wave);

  const int m0 = blockIdx.x * 64 + (wave >> 1) * 32;
  const int n0 = blockIdx.y * 128 + (wave & 1) * 64;
#pragma unroll
  for (int i = 0; i < 2; ++i) {
#pragma unroll
    for (int j = 0; j < 4; ++j) {
      const int n = n0 + j * 16 + l16;
      const float bv = bias[n];
#pragma unroll
      for (int r = 0; r < 4; ++r) {
        const int m = m0 + i * 16 + quad * 4 + r;
        out[(size_t)m * 1024 + n] = acc[i][j][r] + bv;
      }
    }
  }
}

extern "C" void kernel_launch(void* const* d_in, const int* in_sizes, int n_in,
                              void* d_out, int out_size, void* d_ws, size_t ws_size,
                              hipStream_t stream) {
  const float* x      = (const float*)d_in[0];  // [2,2048,1024]
  const float* w_qkv  = (const float*)d_in[1];  // [1024,3072]
  const float* b_qkv  = (const float*)d_in[2];  // [3072]
  const float* w_proj = (const float*)d_in[3];  // [1024,1024]
  const float* b_proj = (const float*)d_in[4];  // [1024]
  float* out = (float*)d_out;                   // [2,2048,1024] fp32

  // workspace layout (ushort elems): Xb 4M | WTq 3M | WTp 1M | QKV 12M | AO 4M = 48 MiB
  unsigned short* Xb  = (unsigned short*)d_ws;
  unsigned short* WTq = Xb + (size_t)4096 * 1024;
  unsigned short* WTp = WTq + (size_t)3072 * 1024;
  unsigned short* QKV = WTp + (size_t)1024 * 1024;
  unsigned short* AO  = QKV + (size_t)3 * 4096 * 1024;

  f32_to_bf16_kernel<<<4096, 256, 0, stream>>>(x, Xb, 4096 * 1024);
  transpose_f32_bf16_kernel<<<dim3(96, 32), dim3(32, 8), 0, stream>>>(w_qkv, WTq, 1024, 3072);
  transpose_f32_bf16_kernel<<<dim3(32, 32), dim3(32, 8), 0, stream>>>(w_proj, WTp, 1024, 1024);
  qkv_gemm_kernel<<<dim3(32, 24), 256, 0, stream>>>(Xb, WTq, b_qkv, QKV);
  attn_kernel<<<512, 256, 0, stream>>>(QKV, AO);
  proj_gemm_kernel<<<dim3(64, 8), 256, 0, stream>>>(AO, WTp, b_proj, out);
}

// Round 5
// 204.973 us; speedup vs baseline: 1.0152x; 1.0152x over previous
//
#include <hip/hip_runtime.h>

// CausalSelfAttention: B=2, S=2048, D=1024, H=16, Hd=64
// qkv = x@w_qkv+b ; per-head causal softmax(QK^T/8)V ; out = ao@w_proj+b
//
// Fragment layouts (gfx950, HW-verified per guide):
//   16x16x32: A[m=lane&15][k=(lane>>4)*8+j]; B[k][n=lane&15]; C/D col=lane&15,
//             row=(lane>>4)*4+reg
//   32x32x16: A[m=lane&31][k=(lane>>5)*8+j]; B[k=(lane>>5)*8+j][n=lane&31];
//             C/D col=lane&31, row=(reg&3)+8*(reg>>2)+4*(lane>>5)  [m74/m101]
//
// R14: qkv rebuilt as a 256x256 multi-phase kernel (T3+T4 schedule):
// 512 thr / 8 waves (2Mx4N), wave tile 128x64, BK=64 split into two k-half
// sub-tiles [buf][kh][256][32] (128 KB dbuf LDS). Per K-tile 4 phases, each
// {2 global_load_lds for t+1 | 4-8 ds_read_b128 | 16 MFMA | barrier};
// counted waits only: vmcnt(2) end of ph0, vmcnt(4) at tile boundary
// (kh1 of the next tile stays in flight) - never vmcnt(0) in-loop.
// Both-sides swizzle c^=(row>>1)&3 (bank-balanced b128). setprio on MFMAs.
// proj: R0-proven 2-barrier mainloop (R4 restructure was null). attn: R3 body.

typedef float f32x4 __attribute__((ext_vector_type(4)));
typedef float f32x16 __attribute__((ext_vector_type(16)));
typedef short bf16x8 __attribute__((ext_vector_type(8)));

#if __has_builtin(__builtin_amdgcn_exp2f)
#define EXP2(x) __builtin_amdgcn_exp2f(x)
#else
#define EXP2(x) exp2f(x)
#endif

__device__ __forceinline__ unsigned short f2bf(float f) {
  union { float f; unsigned u; } v; v.f = f;
  unsigned u = v.u + 0x7fffu + ((v.u >> 16) & 1u);   // RNE
  return (unsigned short)(u >> 16);
}

// async global->LDS, 16 bytes per lane; lds base must be wave-uniform,
// lane l's data lands at lds_base + l*16 bytes (m104/m108 semantics).
__device__ __forceinline__ void async_load16(const void* g, void* lds) {
  __builtin_amdgcn_global_load_lds(
      (const __attribute__((address_space(1))) void*)g,
      (__attribute__((address_space(3))) void*)lds, 16, 0, 0);
}

// ---------------- prep: fp32 -> bf16 elementwise ----------------
__global__ void f32_to_bf16_kernel(const float* __restrict__ in,
                                   unsigned short* __restrict__ out, int n) {
  int i = (blockIdx.x * 256 + threadIdx.x) * 4;
  if (i < n) {
    float4 f = *(const float4*)(in + i);
    ushort4 o;
    o.x = f2bf(f.x); o.y = f2bf(f.y); o.z = f2bf(f.z); o.w = f2bf(f.w);
    *(ushort4*)(out + i) = o;
  }
}

// ---------------- prep: fp32 [K][N] -> bf16 [N][K] ----------------
__global__ void transpose_f32_bf16_kernel(const float* __restrict__ in,
                                          unsigned short* __restrict__ out,
                                          int K, int N) {
  __shared__ float tile[32][33];
  int n0 = blockIdx.x * 32, k0 = blockIdx.y * 32;
  int tx = threadIdx.x, ty = threadIdx.y;  // block (32,8)
#pragma unroll
  for (int i = ty; i < 32; i += 8)
    tile[i][tx] = in[(size_t)(k0 + i) * N + (n0 + tx)];
  __syncthreads();
#pragma unroll
  for (int i = ty; i < 32; i += 8)
    out[(size_t)(n0 + i) * K + (k0 + tx)] = f2bf(tile[tx][i]);
}

// ---------------- basic GEMM mainloop (R0-proven, used by proj) ----------
template <int MI, int NI>
__device__ __forceinline__ void gemm_mainloop(
    const unsigned short* __restrict__ A,   // [M][K] row-major bf16
    const unsigned short* __restrict__ BT,  // [N][K] row-major bf16
    int K, int mBlk, int nBlk,
    unsigned short* As, unsigned short* Bs,
    f32x4 (&acc)[MI][NI], int lane, int wave)
{
  const int l16 = lane & 15, quad = lane >> 4;
  const int mW = (wave >> 1) * MI * 16;
  const int nW = (wave & 1) * NI * 16;
  constexpr int AROWS = 2 * MI * 16;
  constexpr int BROWS = 2 * NI * 16;
  constexpr int AINST = AROWS / 64;
  constexpr int BINST = BROWS / 64;
  const int rl = lane >> 2;           // 16 rows per instruction
  const int cl = (lane & 3) * 8;      // 4 lanes cover one 32-elem row

  for (int k0 = 0; k0 < K; k0 += 32) {
    __syncthreads();
#pragma unroll
    for (int t = 0; t < AINST; ++t) {
      const int rbase = wave * (AROWS / 4) + t * 16;
      async_load16(A + (size_t)(mBlk + rbase + rl) * K + k0 + cl, &As[rbase * 32]);
    }
#pragma unroll
    for (int t = 0; t < BINST; ++t) {
      const int rbase = wave * (BROWS / 4) + t * 16;
      async_load16(BT + (size_t)(nBlk + rbase + rl) * K + k0 + cl, &Bs[rbase * 32]);
    }
    __syncthreads();

    bf16x8 af[MI], bf[NI];
#pragma unroll
    for (int i = 0; i < MI; ++i)
      af[i] = *(const bf16x8*)&As[(mW + i * 16 + l16) * 32 + quad * 8];
#pragma unroll
    for (int j = 0; j < NI; ++j)
      bf[j] = *(const bf16x8*)&Bs[(nW + j * 16 + l16) * 32 + quad * 8];
#pragma unroll
    for (int i = 0; i < MI; ++i)
#pragma unroll
      for (int j = 0; j < NI; ++j)
        acc[i][j] = __builtin_amdgcn_mfma_f32_16x16x32_bf16(af[i], bf[j], acc[i][j], 0, 0, 0);
  }
}

// ---------------- QKV GEMM: 256x256 tile, 4-phase/K-tile, counted vmcnt ---
// Q plane: [2][16][2048][64] pre-scaled by 0.125*log2(e)
// K plane: [2][16][2048][64]
// V plane: TRANSPOSED [2][16][64][2048]
__global__ __launch_bounds__(512, 2) void qkv_gemm_kernel(
    const unsigned short* __restrict__ A,   // x bf16 [4096][1024]
    const unsigned short* __restrict__ WT,  // w_qkv^T bf16 [3072][1024]
    const float* __restrict__ bias,         // [3072]
    unsigned short* __restrict__ QKV)
{
  __shared__ __align__(16) unsigned short Al[2][2][256][32];  // 64 KB
  __shared__ __align__(16) unsigned short Bl[2][2][256][32];  // 64 KB
  const int lane = threadIdx.x & 63;
  const int wave = threadIdx.x >> 6;       // 0..7
  const int l16 = lane & 15, quad = lane >> 4;
  const int wm = wave >> 2, wn = wave & 3; // 2 x 4 wave grid

  // XCD-aware remap: 192 blocks, 24 contiguous per XCD (bijective, 192%8==0)
  const int bid = blockIdx.x;
  const int swz = (bid & 7) * 24 + (bid >> 3);
  const int bx = swz & 15, by = swz >> 4;  // 16 x 12 grid
  const int mBlk = bx * 256, nBlk = by * 256;

  const int srow = wave * 32 + (lane >> 2);  // staging row (16 rows/instr)
  const int scol = lane & 3;                 // 16B slot within 64B row

  // stage one k-half sub-tile's per-wave share (2 instr, 32 rows):
  // LDS dest linear; global source pre-swizzled by c^=(row>>1)&3 (rule 21).
  auto stage = [&](const unsigned short* __restrict__ G, int gRow0,
                   unsigned short (*L)[32], int kOff) {
#pragma unroll
    for (int i = 0; i < 2; ++i) {
      const int row = srow + i * 16;
      const int c = scol ^ ((row >> 1) & 3);
      async_load16(G + (size_t)(gRow0 + row) * 1024 + kOff + c * 8,
                   &L[wave * 32 + i * 16][0]);
    }
  };

  auto rdA = [&](int buf, int kc, int mi) -> bf16x8 {
    const int r = wm * 128 + mi * 16 + l16;
    return *(const bf16x8*)&Al[buf][kc][r][(quad ^ ((r >> 1) & 3)) * 8];
  };
  auto rdB = [&](int buf, int kc, int n) -> bf16x8 {
    const int r = wn * 64 + n * 16 + l16;
    return *(const bf16x8*)&Bl[buf][kc][r][(quad ^ ((r >> 1) & 3)) * 8];
  };

  f32x4 acc[8][4];
  const f32x4 z4 = {0.f, 0.f, 0.f, 0.f};
#pragma unroll
  for (int i = 0; i < 8; ++i)
#pragma unroll
    for (int j = 0; j < 4; ++j) acc[i][j] = z4;

  // prologue: tile 0 -> buf 0 (kh0 A,B then kh1 A,B); wait kh0 only.
  stage(A, mBlk, Al[0][0], 0);
  stage(WT, nBlk, Bl[0][0], 0);
  stage(A, mBlk, Al[0][1], 32);
  stage(WT, nBlk, Bl[0][1], 32);
  asm volatile("s_waitcnt vmcnt(4)\n\ts_barrier" ::: "memory");

  for (int t = 0; t < 16; ++t) {
    const int cur = t & 1, nxt = cur ^ 1;
    const int tn = (t + 1 < 16) ? t + 1 : 15;   // dummy re-stage on last tile
    const int kO = tn * 64;
    bf16x8 bf0[4], bf1[4], af[4];

    // ---- ph0: (m-half 0, k-chunk 0); stage A-kh0(t+1)
    stage(A, mBlk, Al[nxt][0], kO);
#pragma unroll
    for (int n = 0; n < 4; ++n) bf0[n] = rdB(cur, 0, n);
#pragma unroll
    for (int mi = 0; mi < 4; ++mi) af[mi] = rdA(cur, 0, mi);
    __builtin_amdgcn_s_setprio(1);
#pragma unroll
    for (int mi = 0; mi < 4; ++mi)
#pragma unroll
      for (int n = 0; n < 4; ++n)
        acc[mi][n] = __builtin_amdgcn_mfma_f32_16x16x32_bf16(af[mi], bf0[n], acc[mi][n], 0, 0, 0);
    __builtin_amdgcn_s_setprio(0);
    // gate kh1(t) (staged 2-4 phases ago); leave ph0's 2 loads flying
    asm volatile("s_waitcnt vmcnt(2)\n\ts_barrier" ::: "memory");

    // ---- ph1: (m-half 0, k-chunk 1); stage B-kh0(t+1)
    stage(WT, nBlk, Bl[nxt][0], kO);
#pragma unroll
    for (int n = 0; n < 4; ++n) bf1[n] = rdB(cur, 1, n);
#pragma unroll
    for (int mi = 0; mi < 4; ++mi) af[mi] = rdA(cur, 1, mi);
    __builtin_amdgcn_s_setprio(1);
#pragma unroll
    for (int mi = 0; mi < 4; ++mi)
#pragma unroll
      for (int n = 0; n < 4; ++n)
        acc[mi][n] = __builtin_amdgcn_mfma_f32_16x16x32_bf16(af[mi], bf1[n], acc[mi][n], 0, 0, 0);
    __builtin_amdgcn_s_setprio(0);
    asm volatile("s_barrier" ::: "memory");

    // ---- ph2: (m-half 1, k-chunk 0); stage A-kh1(t+1); reuse bf0
    stage(A, mBlk, Al[nxt][1], kO + 32);
#pragma unroll
    for (int mi = 0; mi < 4; ++mi) af[mi] = rdA(cur, 0, mi + 4);
    __builtin_amdgcn_s_setprio(1);
#pragma unroll
    for (int mi = 0; mi < 4; ++mi)
#pragma unroll
      for (int n = 0; n < 4; ++n)
        acc[mi + 4][n] = __builtin_amdgcn_mfma_f32_16x16x32_bf16(af[mi], bf0[n], acc[mi + 4][n], 0, 0, 0);
    __builtin_amdgcn_s_setprio(0);
    asm volatile("s_barrier" ::: "memory");

    // ---- ph3: (m-half 1, k-chunk 1); stage B-kh1(t+1); reuse bf1
    stage(WT, nBlk, Bl[nxt][1], kO + 32);
#pragma unroll
    for (int mi = 0; mi < 4; ++mi) af[mi] = rdA(cur, 1, mi + 4);
    __builtin_amdgcn_s_setprio(1);
#pragma unroll
    for (int mi = 0; mi < 4; ++mi)
#pragma unroll
      for (int n = 0; n < 4; ++n)
        acc[mi + 4][n] = __builtin_amdgcn_mfma_f32_16x16x32_bf16(af[mi], bf1[n], acc[mi + 4][n], 0, 0, 0);
    __builtin_amdgcn_s_setprio(0);
    // boundary: gate kh0(t+1) (ph0/ph1 loads); leave kh1(t+1)'s 4 flying
    asm volatile("s_waitcnt vmcnt(4)\n\ts_barrier" ::: "memory");
  }
  asm volatile("s_waitcnt vmcnt(0)" ::: "memory");  // drain dummy stages

  // ---- epilogue (per wave: 128 x 64 at m0,n0) ----
  const int m0 = mBlk + wm * 128;
  const int n0 = nBlk + wn * 64;
  const int whichW = n0 >> 10;          // uniform per wave (64-aligned)
  const int bb = m0 >> 11;              // uniform per wave (128-aligned)
  const int sBase = (m0 & 2047);
  const size_t planeE = (size_t)2 * 16 * 2048 * 64;

  if (whichW == 2) {                    // V -> transposed store
    unsigned short* Vb = QKV + 2 * planeE;
#pragma unroll
    for (int j = 0; j < 4; ++j) {
      const int rem = (n0 & 1023) + j * 16 + l16;
      const int hh = rem >> 6, hd = rem & 63;
      const float bv = bias[n0 + j * 16 + l16];
      unsigned short* col = Vb + (((size_t)bb * 16 + hh) * 64 + hd) * 2048;
#pragma unroll
      for (int i = 0; i < 8; ++i) {
        unsigned short pk[4];
#pragma unroll
        for (int r = 0; r < 4; ++r) pk[r] = f2bf(acc[i][j][r] + bv);
        *(ushort4*)&col[sBase + i * 16 + quad * 4] = *(ushort4*)pk;
      }
    }
  } else {
    // Q: fold 1/sqrt(Hd) AND log2(e) -> scores come out in log2 domain
    const float scale = (whichW == 0) ? 0.18033688011112042f : 1.0f;
#pragma unroll
    for (int j = 0; j < 4; ++j) {
      const int n = n0 + j * 16 + l16;
      const float bv = bias[n];
      const int rem = n & 1023;
      const int hh = rem >> 6, hd = rem & 63;
      unsigned short* pl = QKV + (size_t)whichW * planeE +
                           (((size_t)bb * 16 + hh) * 2048) * 64 + hd;
#pragma unroll
      for (int r = 0; r < 4; ++r) {
        const int s = sBase + (quad * 4 + r);
#pragma unroll
        for (int i = 0; i < 8; ++i)
          pl[(size_t)(s + i * 16) * 64] = f2bf((acc[i][j][r] + bv) * scale);
      }
    }
  }
}

// ---------------- flash attention (swapped 32x32, in-register P) ----------
// Block = 4 waves x 32 queries = 128 queries of one (b,h). Linear grid 512:
//   xcd = lin&7, slot = lin>>3; col = xcd*4 + (slot>>4); b = col>>4, h = col&15
//   qg = slot<32 ? slot&15 : 15-(slot&15)
// -> each XCD sees only 4 (b,h) columns (2MB K/V, L2-resident); CU c within
// an XCD gets slots c and c+32 -> qg complement pair (balanced work).
// Body is the R1-proven schedule: per tile QK -> softmax -> PV, 3 buffers.
__global__ __launch_bounds__(256, 2) void attn_kernel(
    const unsigned short* __restrict__ QKV,
    unsigned short* __restrict__ AO)         // [2][2048][1024] bf16
{
  __shared__ __align__(16) unsigned short Ks[3 * 64 * 64];  // 24 KB
  __shared__ __align__(16) unsigned short Vs[3 * 64 * 64];  // 24 KB
  const int lane = threadIdx.x & 63;
  const int wave = threadIdx.x >> 6;
  const int l31 = lane & 31;
  const int hi  = lane >> 5;

  const int lin  = blockIdx.x;
  const int xcd  = lin & 7;
  const int slot = lin >> 3;                 // 0..63
  const int col  = xcd * 4 + (slot >> 4);    // 0..31
  const int b = col >> 4, h = col & 15;
  const int qg = (slot < 32) ? (slot & 15) : (15 - (slot & 15));
  const int qw = qg * 128 + wave * 32;       // this wave's first query

  const size_t planeE = (size_t)2 * 16 * 2048 * 64;
  const size_t bhS = ((size_t)b * 16 + h) * (size_t)(2048 * 64);
  const unsigned short* Q   = QKV + bhS;                 // [2048][64], pre-scaled
  const unsigned short* Kg  = QKV + planeE + bhS;        // [2048][64]
  const unsigned short* VTg = QKV + 2 * planeE + bhS;    // [64][2048]

  // Q B-frags: B[k=hd][n=query=l31]; frag t covers hd t*16 + hi*8 .. +7
  bf16x8 qf_[4];
#pragma unroll
  for (int t = 0; t < 4; ++t)
    qf_[t] = *(const bf16x8*)(Q + (size_t)(qw + l31) * 64 + t * 16 + hi * 8);

  bf16x8 onesf;                               // B-frag of bf16(1.0)
#pragma unroll
  for (int i = 0; i < 8; ++i) onesf[i] = (short)0x3F80;

  f32x16 O[2], Osum;
#pragma unroll
  for (int r = 0; r < 16; ++r) { O[0][r] = 0.f; O[1][r] = 0.f; Osum[r] = 0.f; }

  // DMA role: waves 0,1 stage K; waves 2,3 stage V. 4 instr/wave, 1KB each.
  const int tbase = (wave & 1) * 4;
  const bool doV = wave >= 2;

  auto stage = [&](int tileIdx, int bufIdx) {
    const int kt = tileIdx * 64;
    unsigned short* Kb = Ks + bufIdx * 4096;
    unsigned short* Vb = Vs + bufIdx * 4096;
#pragma unroll
    for (int i = 0; i < 4; ++i) {
      const int t = tbase + i;
      const int s = t * 64 + lane;           // 16B slot this lane fills
      const int row = s >> 3;
      const int c = (s & 7) ^ (row & 7);     // un-swizzle: which global 16B
      if (doV)
        async_load16(VTg + (size_t)row * 2048 + kt + c * 8, Vb + t * 512);
      else
        async_load16(Kg + (size_t)(kt + row) * 64 + c * 8, Kb + t * 512);
    }
  };

  const int nt = qg * 2 + 2;                 // staged tiles (covers wave 3)
  stage(0, 0);
  stage(1, 1);
  for (int ti = 0; ti < nt; ++ti) {
    // wait for stage(ti) (leaves the 4 newest = stage(ti+1) in flight),
    // then barrier. NO vmcnt(0) drain — the AITER-style pipeline.
    asm volatile("s_waitcnt vmcnt(4)\n\ts_barrier" ::: "memory");
    const int tn = (ti + 2 < nt) ? ti + 2 : nt - 1;  // dummy re-stage at the end
    stage(tn, (ti + 2) % 3);                 // keeps 4 in flight per wave, always
    const int kt = ti * 64;
    const unsigned short* Kb = Ks + (ti % 3) * 4096;
    const unsigned short* Vb = Vs + (ti % 3) * 4096;

    if (kt <= qw + 31) {
      const bool dmask = (kt + 63 > qw);
#pragma unroll
      for (int kg = 0; kg < 2; ++kg) {
        // K A-frags: A[m=key=l31(+kg*32)][k=hd chunk], swizzled LDS
        const int krow = kg * 32 + l31;
        const int ks7 = krow & 7;
        bf16x8 ka[4];
#pragma unroll
        for (int t = 0; t < 4; ++t)
          ka[t] = *(const bf16x8*)&Kb[(krow * 8 + ((t * 2 + hi) ^ ks7)) * 8];

        f32x16 sc;
#pragma unroll
        for (int r = 0; r < 16; ++r) sc[r] = 0.f;
        __builtin_amdgcn_s_setprio(1);
#pragma unroll
        for (int t = 0; t < 4; ++t)
          sc = __builtin_amdgcn_mfma_f32_32x32x16_bf16(ka[t], qf_[t], sc, 0, 0, 0);
        __builtin_amdgcn_s_setprio(0);

        // softmax term, fully in-register
        float p[16];
#pragma unroll
        for (int r = 0; r < 16; ++r) {
          float v = sc[r];
          if (dmask) {
            const int key = kt + kg * 32 + (r & 3) + 8 * (r >> 2) + 4 * hi;
            if (key > qw + l31) v = -INFINITY;
          }
          p[r] = EXP2(v);                    // native v_exp_f32
        }
        // pack pairs (keys ascend 2-at-a-time within each lane half)
        unsigned c8[8];
#pragma unroll
        for (int i = 0; i < 8; ++i)
          asm("v_cvt_pk_bf16_f32 %0, %1, %2"
              : "=v"(c8[i]) : "v"(p[2 * i]), "v"(p[2 * i + 1]));

#pragma unroll
        for (int half = 0; half < 2; ++half) {
          // assemble PV A-frag for 16-key chunk kc = kg*2+half:
          // lane half 0 needs keys kc*16+0..7, half 1 needs +8..15.
          unsigned a0 = c8[4 * half + 0], a1 = c8[4 * half + 1];
          unsigned a2 = c8[4 * half + 2], a3 = c8[4 * half + 3];
          asm("v_permlane32_swap_b32 %0, %1" : "+v"(a0), "+v"(a2));
          asm("v_permlane32_swap_b32 %0, %1" : "+v"(a1), "+v"(a3));
          union { unsigned u[4]; bf16x8 v; } pa;
          pa.u[0] = a0; pa.u[1] = a1; pa.u[2] = a2; pa.u[3] = a3;
          const int kc = kg * 2 + half;

          __builtin_amdgcn_s_setprio(1);
          // row-sum on the matrix pipe; lands in O's row layout
          Osum = __builtin_amdgcn_mfma_f32_32x32x16_bf16(pa.v, onesf, Osum, 0, 0, 0);
#pragma unroll
          for (int g = 0; g < 2; ++g) {
            const int vrow = g * 32 + l31;   // hd row of V^T
            bf16x8 vb = *(const bf16x8*)&Vb[(vrow * 8 + ((kc * 2 + hi) ^ (vrow & 7))) * 8];
            O[g] = __builtin_amdgcn_mfma_f32_32x32x16_bf16(pa.v, vb, O[g], 0, 0, 0);
          }
          __builtin_amdgcn_s_setprio(0);
        }
      }
    }
  }

  // epilogue: normalize by Osum (already per-row, replicated across lanes)
  unsigned short* base = AO + ((size_t)b * 2048 + qw) * 1024 + h * 64 + l31;
#pragma unroll
  for (int r = 0; r < 16; ++r) {
    const float inv = 1.0f / Osum[r];
    const int row = (r & 3) + 8 * (r >> 2) + 4 * hi;
#pragma unroll
    for (int g = 0; g < 2; ++g)
      base[(size_t)row * 1024 + g * 32] = f2bf(O[g][r] * inv);
  }
}

// ---------------- proj GEMM: [4096,1024]x[1024,1024] + bias -> fp32 out ----------------
// 64x128 block tile -> grid 64x8 = 512 blocks (2/CU)
__global__ __launch_bounds__(256) void proj_gemm_kernel(
    const unsigned short* __restrict__ A,   // AO bf16 [4096][1024]
    const unsigned short* __restrict__ WT,  // w_proj^T bf16 [1024][1024]
    const float* __restrict__ bias,         // [1024]
    float* __restrict__ out)                // [4096][1024] fp32
{
  __shared__ unsigned short As[64 * 32];
  __shared__ unsigned short Bs[128 * 32];
  const int lane = threadIdx.x & 63;
  const int wave = threadIdx.x >> 6;
  const int l16 = lane & 15, quad = lane >> 4;

  f32x4 acc[2][4];
  const f32x4 z4 = {0.f, 0.f, 0.f, 0.f};
#pragma unroll
  for (int i = 0; i < 2; ++i)
#pragma unroll
    for (int j = 0; j < 4; ++j) acc[i][j] = z4;

  gemm_mainloop<2, 4>(A, WT, 1024, blockIdx.x * 64, blockIdx.y * 128,
                      As, Bs, acc, lane, wave);

  const int m0 = blockIdx.x * 64 + (wave >> 1) * 32;
  const int n0 = blockIdx.y * 128 + (wave & 1) * 64;
#pragma unroll
  for (int i = 0; i < 2; ++i) {
#pragma unroll
    for (int j = 0; j < 4; ++j) {
      const int n = n0 + j * 16 + l16;
      const float bv = bias[n];
#pragma unroll
      for (int r = 0; r < 4; ++r) {
        const int m = m0 + i * 16 + quad * 4 + r;
        out[(size_t)m * 1024 + n] = acc[i][j][r] + bv;
      }
    }
  }
}

extern "C" void kernel_launch(void* const* d_in, const int* in_sizes, int n_in,
                              void* d_out, int out_size, void* d_ws, size_t ws_size,
                              hipStream_t stream) {
  const float* x      = (const float*)d_in[0];  // [2,2048,1024]
  const float* w_qkv  = (const float*)d_in[1];  // [1024,3072]
  const float* b_qkv  = (const float*)d_in[2];  // [3072]
  const float* w_proj = (const float*)d_in[3];  // [1024,1024]
  const float* b_proj = (const float*)d_in[4];  // [1024]
  float* out = (float*)d_out;                   // [2,2048,1024] fp32

  // workspace layout (ushort elems): Xb 4M | WTq 3M | WTp 1M | QKV 12M | AO 4M = 48 MiB
  unsigned short* Xb  = (unsigned short*)d_ws;
  unsigned short* WTq = Xb + (size_t)4096 * 1024;
  unsigned short* WTp = WTq + (size_t)3072 * 1024;
  unsigned short* QKV = WTp + (size_t)1024 * 1024;
  unsigned short* AO  = QKV + (size_t)3 * 4096 * 1024;

  f32_to_bf16_kernel<<<4096, 256, 0, stream>>>(x, Xb, 4096 * 1024);
  transpose_f32_bf16_kernel<<<dim3(96, 32), dim3(32, 8), 0, stream>>>(w_qkv, WTq, 1024, 3072);
  transpose_f32_bf16_kernel<<<dim3(32, 32), dim3(32, 8), 0, stream>>>(w_proj, WTp, 1024, 1024);
  qkv_gemm_kernel<<<192, 512, 0, stream>>>(Xb, WTq, b_qkv, QKV);
  attn_kernel<<<512, 256, 0, stream>>>(QKV, AO);
  proj_gemm_kernel<<<dim3(64, 8), 256, 0, stream>>>(AO, WTp, b_proj, out);
}

// Round 7
// 203.331 us; speedup vs baseline: 1.0234x; 1.0081x over previous
//
#include <hip/hip_runtime.h>

// CausalSelfAttention: B=2, S=2048, D=1024, H=16, Hd=64
// qkv = x@w_qkv+b ; per-head causal softmax(QK^T/8)V ; out = ao@w_proj+b
//
// Fragment layouts (gfx950, HW-verified per guide):
//   16x16x32: A[m=lane&15][k=(lane>>4)*8+j]; B[k][n=lane&15]; C/D col=lane&15,
//             row=(lane>>4)*4+reg
//   32x32x16: A[m=lane&31][k=(lane>>5)*8+j]; B[k=(lane>>5)*8+j][n=lane&31];
//             C/D col=lane&31, row=(reg&3)+8*(reg>>2)+4*(lane>>5)  [m74/m101]
//
// R16 = R15 resubmitted (container infra failure, no kernel verdict).
// qkv = faithful m201-style 8-phase 256x256 kernel. Per K-tile, 4 phases
// keyed (kh, mh); each phase = {stage 1 half(t+1) | ds_read frags} -> BARRIER
// -> setprio+16 MFMA+setprio -> BARRIER (two barriers/phase => wave
// role-split: reads overlap other waves' MFMA). Counted waits ONLY at
// ph1-end / ph3-end: vmcnt(4) (ledger: 4->6->8->wait->4, never 0; retires
// exactly the kh-half the next 2 phases read; barrier after wait gives
// cross-wave visibility). LDS [2buf][2kh][256][32], swizzle c^=(row>>1)&3
// both sides (R5-proven). XCD map: 24 blocks/XCD as 4bx x 6by (A 2MB + B 3MB
// ~ L2-resident, bijective). attn: R3-passing body. proj: R0 mainloop.

typedef float f32x4 __attribute__((ext_vector_type(4)));
typedef float f32x16 __attribute__((ext_vector_type(16)));
typedef short bf16x8 __attribute__((ext_vector_type(8)));

#if __has_builtin(__builtin_amdgcn_exp2f)
#define EXP2(x) __builtin_amdgcn_exp2f(x)
#else
#define EXP2(x) exp2f(x)
#endif

__device__ __forceinline__ unsigned short f2bf(float f) {
  union { float f; unsigned u; } v; v.f = f;
  unsigned u = v.u + 0x7fffu + ((v.u >> 16) & 1u);   // RNE
  return (unsigned short)(u >> 16);
}

// async global->LDS, 16 bytes per lane; lds base must be wave-uniform,
// lane l's data lands at lds_base + l*16 bytes (m104/m108 semantics).
__device__ __forceinline__ void async_load16(const void* g, void* lds) {
  __builtin_amdgcn_global_load_lds(
      (const __attribute__((address_space(1))) void*)g,
      (__attribute__((address_space(3))) void*)lds, 16, 0, 0);
}

// ---------------- prep: fp32 -> bf16 elementwise ----------------
__global__ void f32_to_bf16_kernel(const float* __restrict__ in,
                                   unsigned short* __restrict__ out, int n) {
  int i = (blockIdx.x * 256 + threadIdx.x) * 4;
  if (i < n) {
    float4 f = *(const float4*)(in + i);
    ushort4 o;
    o.x = f2bf(f.x); o.y = f2bf(f.y); o.z = f2bf(f.z); o.w = f2bf(f.w);
    *(ushort4*)(out + i) = o;
  }
}

// ---------------- prep: fp32 [K][N] -> bf16 [N][K] ----------------
__global__ void transpose_f32_bf16_kernel(const float* __restrict__ in,
                                          unsigned short* __restrict__ out,
                                          int K, int N) {
  __shared__ float tile[32][33];
  int n0 = blockIdx.x * 32, k0 = blockIdx.y * 32;
  int tx = threadIdx.x, ty = threadIdx.y;  // block (32,8)
#pragma unroll
  for (int i = ty; i < 32; i += 8)
    tile[i][tx] = in[(size_t)(k0 + i) * N + (n0 + tx)];
  __syncthreads();
#pragma unroll
  for (int i = ty; i < 32; i += 8)
    out[(size_t)(n0 + i) * K + (k0 + tx)] = f2bf(tile[tx][i]);
}

// ---------------- basic GEMM mainloop (R0-proven, used by proj) ----------
template <int MI, int NI>
__device__ __forceinline__ void gemm_mainloop(
    const unsigned short* __restrict__ A,   // [M][K] row-major bf16
    const unsigned short* __restrict__ BT,  // [N][K] row-major bf16
    int K, int mBlk, int nBlk,
    unsigned short* As, unsigned short* Bs,
    f32x4 (&acc)[MI][NI], int lane, int wave)
{
  const int l16 = lane & 15, quad = lane >> 4;
  const int mW = (wave >> 1) * MI * 16;
  const int nW = (wave & 1) * NI * 16;
  constexpr int AROWS = 2 * MI * 16;
  constexpr int BROWS = 2 * NI * 16;
  constexpr int AINST = AROWS / 64;
  constexpr int BINST = BROWS / 64;
  const int rl = lane >> 2;           // 16 rows per instruction
  const int cl = (lane & 3) * 8;      // 4 lanes cover one 32-elem row

  for (int k0 = 0; k0 < K; k0 += 32) {
    __syncthreads();
#pragma unroll
    for (int t = 0; t < AINST; ++t) {
      const int rbase = wave * (AROWS / 4) + t * 16;
      async_load16(A + (size_t)(mBlk + rbase + rl) * K + k0 + cl, &As[rbase * 32]);
    }
#pragma unroll
    for (int t = 0; t < BINST; ++t) {
      const int rbase = wave * (BROWS / 4) + t * 16;
      async_load16(BT + (size_t)(nBlk + rbase + rl) * K + k0 + cl, &Bs[rbase * 32]);
    }
    __syncthreads();

    bf16x8 af[MI], bf[NI];
#pragma unroll
    for (int i = 0; i < MI; ++i)
      af[i] = *(const bf16x8*)&As[(mW + i * 16 + l16) * 32 + quad * 8];
#pragma unroll
    for (int j = 0; j < NI; ++j)
      bf[j] = *(const bf16x8*)&Bs[(nW + j * 16 + l16) * 32 + quad * 8];
#pragma unroll
    for (int i = 0; i < MI; ++i)
#pragma unroll
      for (int j = 0; j < NI; ++j)
        acc[i][j] = __builtin_amdgcn_mfma_f32_16x16x32_bf16(af[i], bf[j], acc[i][j], 0, 0, 0);
  }
}

// ---------------- QKV GEMM: 256x256, 8-phase (2 barriers/phase) ----------
// Q plane: [2][16][2048][64] pre-scaled by 0.125*log2(e)
// K plane: [2][16][2048][64]
// V plane: TRANSPOSED [2][16][64][2048]
__global__ __launch_bounds__(512, 2) void qkv_gemm_kernel(
    const unsigned short* __restrict__ A,   // x bf16 [4096][1024]
    const unsigned short* __restrict__ WT,  // w_qkv^T bf16 [3072][1024]
    const float* __restrict__ bias,         // [3072]
    unsigned short* __restrict__ QKV)
{
  __shared__ __align__(16) unsigned short Al[2][2][256][32];  // 64 KB
  __shared__ __align__(16) unsigned short Bl[2][2][256][32];  // 64 KB
  const int lane = threadIdx.x & 63;
  const int wave = threadIdx.x >> 6;       // 0..7
  const int l16 = lane & 15, quad = lane >> 4;
  const int wm = wave >> 2, wn = wave & 3; // 2 x 4 wave grid

  // XCD map: 192 blocks; XCD x owns a 4bx x 6by rectangle (bijective).
  const int bid = blockIdx.x;
  const int xcd = bid & 7, rb = bid >> 3;            // rb in [0,24)
  const int bx = (xcd & 3) * 4 + (rb & 3);           // [0,16)
  const int by = (xcd >> 2) * 6 + (rb >> 2);         // [0,12)
  const int mBlk = bx * 256, nBlk = by * 256;

  const int srow = wave * 32 + (lane >> 2);  // staging row (16 rows/instr)
  const int scol = lane & 3;                 // 16B slot within 64B row

  // stage one kh sub-tile's per-wave share (2 instr, 32 rows):
  // LDS dest linear; global source pre-swizzled by c^=(row>>1)&3 (rule 21).
  auto stage = [&](const unsigned short* __restrict__ G, int gRow0,
                   unsigned short (*L)[32], int kOff) {
#pragma unroll
    for (int i = 0; i < 2; ++i) {
      const int row = srow + i * 16;
      const int c = scol ^ ((row >> 1) & 3);
      async_load16(G + (size_t)(gRow0 + row) * 1024 + kOff + c * 8,
                   &L[wave * 32 + i * 16][0]);
    }
  };

  auto rdA = [&](int buf, int kh, int mi) -> bf16x8 {
    const int r = wm * 128 + mi * 16 + l16;
    return *(const bf16x8*)&Al[buf][kh][r][(quad ^ ((r >> 1) & 3)) * 8];
  };
  auto rdB = [&](int buf, int kh, int n) -> bf16x8 {
    const int r = wn * 64 + n * 16 + l16;
    return *(const bf16x8*)&Bl[buf][kh][r][(quad ^ ((r >> 1) & 3)) * 8];
  };

  f32x4 acc[8][4];
  const f32x4 z4 = {0.f, 0.f, 0.f, 0.f};
#pragma unroll
  for (int i = 0; i < 8; ++i)
#pragma unroll
    for (int j = 0; j < 4; ++j) acc[i][j] = z4;

  // prologue: tile 0 -> buf 0; gate kh0, leave kh1 (4 loads) in flight.
  stage(A, mBlk, Al[0][0], 0);
  stage(WT, nBlk, Bl[0][0], 0);
  stage(A, mBlk, Al[0][1], 32);
  stage(WT, nBlk, Bl[0][1], 32);
  asm volatile("s_waitcnt vmcnt(4)\n\ts_barrier" ::: "memory");

  for (int t = 0; t < 16; ++t) {
    const int cur = t & 1, nxt = cur ^ 1;
    const int tn = (t + 1 < 16) ? t + 1 : 15;   // dummy re-stage on last tile
    const int kO = tn * 64;
    bf16x8 bf[4], af[4];

    // ---- ph0 (kh0, mh0): stage A-kh0(t+1); read 4B+4A; bar; MFMA; bar
    stage(A, mBlk, Al[nxt][0], kO);
#pragma unroll
    for (int n = 0; n < 4; ++n) bf[n] = rdB(cur, 0, n);
#pragma unroll
    for (int i = 0; i < 4; ++i) af[i] = rdA(cur, 0, i);
    asm volatile("s_barrier" ::: "memory");
    __builtin_amdgcn_s_setprio(1);
#pragma unroll
    for (int i = 0; i < 4; ++i)
#pragma unroll
      for (int n = 0; n < 4; ++n)
        acc[i][n] = __builtin_amdgcn_mfma_f32_16x16x32_bf16(af[i], bf[n], acc[i][n], 0, 0, 0);
    __builtin_amdgcn_s_setprio(0);
    asm volatile("s_barrier" ::: "memory");

    // ---- ph1 (kh0, mh1): stage B-kh0(t+1); read 4A (reuse bf); bar; MFMA;
    //      vmcnt(4) -> retires kh1(t), leaves kh0(t+1) flying; bar
    stage(WT, nBlk, Bl[nxt][0], kO);
#pragma unroll
    for (int i = 0; i < 4; ++i) af[i] = rdA(cur, 0, 4 + i);
    asm volatile("s_barrier" ::: "memory");
    __builtin_amdgcn_s_setprio(1);
#pragma unroll
    for (int i = 0; i < 4; ++i)
#pragma unroll
      for (int n = 0; n < 4; ++n)
        acc[4 + i][n] = __builtin_amdgcn_mfma_f32_16x16x32_bf16(af[i], bf[n], acc[4 + i][n], 0, 0, 0);
    __builtin_amdgcn_s_setprio(0);
    asm volatile("s_waitcnt vmcnt(4)\n\ts_barrier" ::: "memory");

    // ---- ph2 (kh1, mh0): stage A-kh1(t+1); read 4B+4A; bar; MFMA; bar
    stage(A, mBlk, Al[nxt][1], kO + 32);
#pragma unroll
    for (int n = 0; n < 4; ++n) bf[n] = rdB(cur, 1, n);
#pragma unroll
    for (int i = 0; i < 4; ++i) af[i] = rdA(cur, 1, i);
    asm volatile("s_barrier" ::: "memory");
    __builtin_amdgcn_s_setprio(1);
#pragma unroll
    for (int i = 0; i < 4; ++i)
#pragma unroll
      for (int n = 0; n < 4; ++n)
        acc[i][n] = __builtin_amdgcn_mfma_f32_16x16x32_bf16(af[i], bf[n], acc[i][n], 0, 0, 0);
    __builtin_amdgcn_s_setprio(0);
    asm volatile("s_barrier" ::: "memory");

    // ---- ph3 (kh1, mh1): stage B-kh1(t+1); read 4A (reuse bf); bar; MFMA;
    //      vmcnt(4) -> retires kh0(t+1), leaves kh1(t+1) flying; bar
    stage(WT, nBlk, Bl[nxt][1], kO + 32);
#pragma unroll
    for (int i = 0; i < 4; ++i) af[i] = rdA(cur, 1, 4 + i);
    asm volatile("s_barrier" ::: "memory");
    __builtin_amdgcn_s_setprio(1);
#pragma unroll
    for (int i = 0; i < 4; ++i)
#pragma unroll
      for (int n = 0; n < 4; ++n)
        acc[4 + i][n] = __builtin_amdgcn_mfma_f32_16x16x32_bf16(af[i], bf[n], acc[4 + i][n], 0, 0, 0);
    __builtin_amdgcn_s_setprio(0);
    asm volatile("s_waitcnt vmcnt(4)\n\ts_barrier" ::: "memory");
  }
  asm volatile("s_waitcnt vmcnt(0)" ::: "memory");  // drain dummy stages

  // ---- epilogue (per wave: 128 x 64 at m0,n0) ----
  const int m0 = mBlk + wm * 128;
  const int n0 = nBlk + wn * 64;
  const int whichW = n0 >> 10;          // uniform per wave (64-aligned)
  const int bb = m0 >> 11;              // uniform per wave (128-aligned)
  const int sBase = (m0 & 2047);
  const size_t planeE = (size_t)2 * 16 * 2048 * 64;

  if (whichW == 2) {                    // V -> transposed store
    unsigned short* Vb = QKV + 2 * planeE;
#pragma unroll
    for (int j = 0; j < 4; ++j) {
      const int rem = (n0 & 1023) + j * 16 + l16;
      const int hh = rem >> 6, hd = rem & 63;
      const float bv = bias[n0 + j * 16 + l16];
      unsigned short* col = Vb + (((size_t)bb * 16 + hh) * 64 + hd) * 2048;
#pragma unroll
      for (int i = 0; i < 8; ++i) {
        unsigned short pk[4];
#pragma unroll
        for (int r = 0; r < 4; ++r) pk[r] = f2bf(acc[i][j][r] + bv);
        *(ushort4*)&col[sBase + i * 16 + quad * 4] = *(ushort4*)pk;
      }
    }
  } else {
    // Q: fold 1/sqrt(Hd) AND log2(e) -> scores come out in log2 domain
    const float scale = (whichW == 0) ? 0.18033688011112042f : 1.0f;
#pragma unroll
    for (int j = 0; j < 4; ++j) {
      const int n = n0 + j * 16 + l16;
      const float bv = bias[n];
      const int rem = n & 1023;
      const int hh = rem >> 6, hd = rem & 63;
      unsigned short* pl = QKV + (size_t)whichW * planeE +
                           (((size_t)bb * 16 + hh) * 2048) * 64 + hd;
#pragma unroll
      for (int r = 0; r < 4; ++r) {
        const int s = sBase + (quad * 4 + r);
#pragma unroll
        for (int i = 0; i < 8; ++i)
          pl[(size_t)(s + i * 16) * 64] = f2bf((acc[i][j][r] + bv) * scale);
      }
    }
  }
}

// ---------------- flash attention (swapped 32x32, in-register P) ----------
// Block = 4 waves x 32 queries = 128 queries of one (b,h). Linear grid 512:
//   xcd = lin&7, slot = lin>>3; col = xcd*4 + (slot>>4); b = col>>4, h = col&15
//   qg = slot<32 ? slot&15 : 15-(slot&15)
// -> each XCD sees only 4 (b,h) columns (2MB K/V, L2-resident); CU c within
// an XCD gets slots c and c+32 -> qg complement pair (balanced work).
// Body is the R1-proven schedule: per tile QK -> softmax -> PV, 3 buffers.
__global__ __launch_bounds__(256, 2) void attn_kernel(
    const unsigned short* __restrict__ QKV,
    unsigned short* __restrict__ AO)         // [2][2048][1024] bf16
{
  __shared__ __align__(16) unsigned short Ks[3 * 64 * 64];  // 24 KB
  __shared__ __align__(16) unsigned short Vs[3 * 64 * 64];  // 24 KB
  const int lane = threadIdx.x & 63;
  const int wave = threadIdx.x >> 6;
  const int l31 = lane & 31;
  const int hi  = lane >> 5;

  const int lin  = blockIdx.x;
  const int xcd  = lin & 7;
  const int slot = lin >> 3;                 // 0..63
  const int col  = xcd * 4 + (slot >> 4);    // 0..31
  const int b = col >> 4, h = col & 15;
  const int qg = (slot < 32) ? (slot & 15) : (15 - (slot & 15));
  const int qw = qg * 128 + wave * 32;       // this wave's first query

  const size_t planeE = (size_t)2 * 16 * 2048 * 64;
  const size_t bhS = ((size_t)b * 16 + h) * (size_t)(2048 * 64);
  const unsigned short* Q   = QKV + bhS;                 // [2048][64], pre-scaled
  const unsigned short* Kg  = QKV + planeE + bhS;        // [2048][64]
  const unsigned short* VTg = QKV + 2 * planeE + bhS;    // [64][2048]

  // Q B-frags: B[k=hd][n=query=l31]; frag t covers hd t*16 + hi*8 .. +7
  bf16x8 qf_[4];
#pragma unroll
  for (int t = 0; t < 4; ++t)
    qf_[t] = *(const bf16x8*)(Q + (size_t)(qw + l31) * 64 + t * 16 + hi * 8);

  bf16x8 onesf;                               // B-frag of bf16(1.0)
#pragma unroll
  for (int i = 0; i < 8; ++i) onesf[i] = (short)0x3F80;

  f32x16 O[2], Osum;
#pragma unroll
  for (int r = 0; r < 16; ++r) { O[0][r] = 0.f; O[1][r] = 0.f; Osum[r] = 0.f; }

  // DMA role: waves 0,1 stage K; waves 2,3 stage V. 4 instr/wave, 1KB each.
  const int tbase = (wave & 1) * 4;
  const bool doV = wave >= 2;

  auto stage = [&](int tileIdx, int bufIdx) {
    const int kt = tileIdx * 64;
    unsigned short* Kb = Ks + bufIdx * 4096;
    unsigned short* Vb = Vs + bufIdx * 4096;
#pragma unroll
    for (int i = 0; i < 4; ++i) {
      const int t = tbase + i;
      const int s = t * 64 + lane;           // 16B slot this lane fills
      const int row = s >> 3;
      const int c = (s & 7) ^ (row & 7);     // un-swizzle: which global 16B
      if (doV)
        async_load16(VTg + (size_t)row * 2048 + kt + c * 8, Vb + t * 512);
      else
        async_load16(Kg + (size_t)(kt + row) * 64 + c * 8, Kb + t * 512);
    }
  };

  const int nt = qg * 2 + 2;                 // staged tiles (covers wave 3)
  stage(0, 0);
  stage(1, 1);
  for (int ti = 0; ti < nt; ++ti) {
    // wait for stage(ti) (leaves the 4 newest = stage(ti+1) in flight),
    // then barrier. NO vmcnt(0) drain — the AITER-style pipeline.
    asm volatile("s_waitcnt vmcnt(4)\n\ts_barrier" ::: "memory");
    const int tn = (ti + 2 < nt) ? ti + 2 : nt - 1;  // dummy re-stage at the end
    stage(tn, (ti + 2) % 3);                 // keeps 4 in flight per wave, always
    const int kt = ti * 64;
    const unsigned short* Kb = Ks + (ti % 3) * 4096;
    const unsigned short* Vb = Vs + (ti % 3) * 4096;

    if (kt <= qw + 31) {
      const bool dmask = (kt + 63 > qw);
#pragma unroll
      for (int kg = 0; kg < 2; ++kg) {
        // K A-frags: A[m=key=l31(+kg*32)][k=hd chunk], swizzled LDS
        const int krow = kg * 32 + l31;
        const int ks7 = krow & 7;
        bf16x8 ka[4];
#pragma unroll
        for (int t = 0; t < 4; ++t)
          ka[t] = *(const bf16x8*)&Kb[(krow * 8 + ((t * 2 + hi) ^ ks7)) * 8];

        f32x16 sc;
#pragma unroll
        for (int r = 0; r < 16; ++r) sc[r] = 0.f;
        __builtin_amdgcn_s_setprio(1);
#pragma unroll
        for (int t = 0; t < 4; ++t)
          sc = __builtin_amdgcn_mfma_f32_32x32x16_bf16(ka[t], qf_[t], sc, 0, 0, 0);
        __builtin_amdgcn_s_setprio(0);

        // softmax term, fully in-register
        float p[16];
#pragma unroll
        for (int r = 0; r < 16; ++r) {
          float v = sc[r];
          if (dmask) {
            const int key = kt + kg * 32 + (r & 3) + 8 * (r >> 2) + 4 * hi;
            if (key > qw + l31) v = -INFINITY;
          }
          p[r] = EXP2(v);                    // native v_exp_f32
        }
        // pack pairs (keys ascend 2-at-a-time within each lane half)
        unsigned c8[8];
#pragma unroll
        for (int i = 0; i < 8; ++i)
          asm("v_cvt_pk_bf16_f32 %0, %1, %2"
              : "=v"(c8[i]) : "v"(p[2 * i]), "v"(p[2 * i + 1]));

#pragma unroll
        for (int half = 0; half < 2; ++half) {
          // assemble PV A-frag for 16-key chunk kc = kg*2+half:
          // lane half 0 needs keys kc*16+0..7, half 1 needs +8..15.
          unsigned a0 = c8[4 * half + 0], a1 = c8[4 * half + 1];
          unsigned a2 = c8[4 * half + 2], a3 = c8[4 * half + 3];
          asm("v_permlane32_swap_b32 %0, %1" : "+v"(a0), "+v"(a2));
          asm("v_permlane32_swap_b32 %0, %1" : "+v"(a1), "+v"(a3));
          union { unsigned u[4]; bf16x8 v; } pa;
          pa.u[0] = a0; pa.u[1] = a1; pa.u[2] = a2; pa.u[3] = a3;
          const int kc = kg * 2 + half;

          __builtin_amdgcn_s_setprio(1);
          // row-sum on the matrix pipe; lands in O's row layout
          Osum = __builtin_amdgcn_mfma_f32_32x32x16_bf16(pa.v, onesf, Osum, 0, 0, 0);
#pragma unroll
          for (int g = 0; g < 2; ++g) {
            const int vrow = g * 32 + l31;   // hd row of V^T
            bf16x8 vb = *(const bf16x8*)&Vb[(vrow * 8 + ((kc * 2 + hi) ^ (vrow & 7))) * 8];
            O[g] = __builtin_amdgcn_mfma_f32_32x32x16_bf16(pa.v, vb, O[g], 0, 0, 0);
          }
          __builtin_amdgcn_s_setprio(0);
        }
      }
    }
  }

  // epilogue: normalize by Osum (already per-row, replicated across lanes)
  unsigned short* base = AO + ((size_t)b * 2048 + qw) * 1024 + h * 64 + l31;
#pragma unroll
  for (int r = 0; r < 16; ++r) {
    const float inv = 1.0f / Osum[r];
    const int row = (r & 3) + 8 * (r >> 2) + 4 * hi;
#pragma unroll
    for (int g = 0; g < 2; ++g)
      base[(size_t)row * 1024 + g * 32] = f2bf(O[g][r] * inv);
  }
}

// ---------------- proj GEMM: [4096,1024]x[1024,1024] + bias -> fp32 out ----------------
// 64x128 block tile -> grid 64x8 = 512 blocks (2/CU)
__global__ __launch_bounds__(256) void proj_gemm_kernel(
    const unsigned short* __restrict__ A,   // AO bf16 [4096][1024]
    const unsigned short* __restrict__ WT,  // w_proj^T bf16 [1024][1024]
    const float* __restrict__ bias,         // [1024]
    float* __restrict__ out)                // [4096][1024] fp32
{
  __shared__ unsigned short As[64 * 32];
  __shared__ unsigned short Bs[128 * 32];
  const int lane = threadIdx.x & 63;
  const int wave = threadIdx.x >> 6;
  const int l16 = lane & 15, quad = lane >> 4;

  f32x4 acc[2][4];
  const f32x4 z4 = {0.f, 0.f, 0.f, 0.f};
#pragma unroll
  for (int i = 0; i < 2; ++i)
#pragma unroll
    for (int j = 0; j < 4; ++j) acc[i][j] = z4;

  gemm_mainloop<2, 4>(A, WT, 1024, blockIdx.x * 64, blockIdx.y * 128,
                      As, Bs, acc, lane, wave);

  const int m0 = blockIdx.x * 64 + (wave >> 1) * 32;
  const int n0 = blockIdx.y * 128 + (wave & 1) * 64;
#pragma unroll
  for (int i = 0; i < 2; ++i) {
#pragma unroll
    for (int j = 0; j < 4; ++j) {
      const int n = n0 + j * 16 + l16;
      const float bv = bias[n];
#pragma unroll
      for (int r = 0; r < 4; ++r) {
        const int m = m0 + i * 16 + quad * 4 + r;
        out[(size_t)m * 1024 + n] = acc[i][j][r] + bv;
      }
    }
  }
}

extern "C" void kernel_launch(void* const* d_in, const int* in_sizes, int n_in,
                              void* d_out, int out_size, void* d_ws, size_t ws_size,
                              hipStream_t stream) {
  const float* x      = (const float*)d_in[0];  // [2,2048,1024]
  const float* w_qkv  = (const float*)d_in[1];  // [1024,3072]
  const float* b_qkv  = (const float*)d_in[2];  // [3072]
  const float* w_proj = (const float*)d_in[3];  // [1024,1024]
  const float* b_proj = (const float*)d_in[4];  // [1024]
  float* out = (float*)d_out;                   // [2,2048,1024] fp32

  // workspace layout (ushort elems): Xb 4M | WTq 3M | WTp 1M | QKV 12M | AO 4M = 48 MiB
  unsigned short* Xb  = (unsigned short*)d_ws;
  unsigned short* WTq = Xb + (size_t)4096 * 1024;
  unsigned short* WTp = WTq + (size_t)3072 * 1024;
  unsigned short* QKV = WTp + (size_t)1024 * 1024;
  unsigned short* AO  = QKV + (size_t)3 * 4096 * 1024;

  f32_to_bf16_kernel<<<4096, 256, 0, stream>>>(x, Xb, 4096 * 1024);
  transpose_f32_bf16_kernel<<<dim3(96, 32), dim3(32, 8), 0, stream>>>(w_qkv, WTq, 1024, 3072);
  transpose_f32_bf16_kernel<<<dim3(32, 32), dim3(32, 8), 0, stream>>>(w_proj, WTp, 1024, 1024);
  qkv_gemm_kernel<<<192, 512, 0, stream>>>(Xb, WTq, b_qkv, QKV);
  attn_kernel<<<512, 256, 0, stream>>>(QKV, AO);
  proj_gemm_kernel<<<dim3(64, 8), 256, 0, stream>>>(AO, WTp, b_proj, out);
}

// Round 8
// 195.810 us; speedup vs baseline: 1.0627x; 1.0384x over previous
//
#include <hip/hip_runtime.h>

// CausalSelfAttention: B=2, S=2048, D=1024, H=16, Hd=64
// qkv = x@w_qkv+b ; per-head causal softmax(QK^T/8)V ; out = ao@w_proj+b
//
// Fragment layouts (gfx950, HW-verified per guide):
//   16x16x32: A[m=lane&15][k=(lane>>4)*8+j]; B[k][n=lane&15]; C/D col=lane&15,
//             row=(lane>>4)*4+reg
//   32x32x16: A[m=lane&31][k=(lane>>5)*8+j]; B[k=(lane>>5)*8+j][n=lane&31];
//             C/D col=lane&31, row=(reg&3)+8*(reg>>2)+4*(lane>>5)  [m74/m101]
//
// R17: qkv = 256x256 double-buffered loop with TWO barriers per K-tile
// (T3 "minimum" recipe): per kh-half {stage kh(t+1) A+B (4 DMA) | 12
// ds_read_b128 | 32 MFMA | s_waitcnt vmcnt(4)+s_barrier}. Ledger (simulated):
// 8 -> wait(4) -> 4 steady state; the retired half is exactly the half the
// next two phases read; never vmcnt(0) in-loop; dummy re-stage on last tile;
// vmcnt(0) after loop. R7's 6 extra barriers removed: any stage-vs-read
// hazard is >= 2 barriers apart (wave skew safe), and waves can now overlap
// one wave's ds_read latency with another's MFMA instead of block-wide
// lockstep [all-read][all-MFMA]. Swizzle c^=(row>>1)&3 both sides; XCD rect
// map (24 blocks/XCD as 4bx x 6by, FETCH 37->20.6MB proven R7).
// prep: 3 kernels fused into 1 (flat grid partition) - 2 fewer launch gaps.
// attn: R3-passing body. proj: R0 mainloop.

typedef float f32x4 __attribute__((ext_vector_type(4)));
typedef float f32x16 __attribute__((ext_vector_type(16)));
typedef short bf16x8 __attribute__((ext_vector_type(8)));

#if __has_builtin(__builtin_amdgcn_exp2f)
#define EXP2(x) __builtin_amdgcn_exp2f(x)
#else
#define EXP2(x) exp2f(x)
#endif

__device__ __forceinline__ unsigned short f2bf(float f) {
  union { float f; unsigned u; } v; v.f = f;
  unsigned u = v.u + 0x7fffu + ((v.u >> 16) & 1u);   // RNE
  return (unsigned short)(u >> 16);
}

// async global->LDS, 16 bytes per lane; lds base must be wave-uniform,
// lane l's data lands at lds_base + l*16 bytes (m104/m108 semantics).
__device__ __forceinline__ void async_load16(const void* g, void* lds) {
  __builtin_amdgcn_global_load_lds(
      (const __attribute__((address_space(1))) void*)g,
      (__attribute__((address_space(3))) void*)lds, 16, 0, 0);
}

// ---------------- fused prep: x->bf16 + both weight transposes ----------
// grid 8192 x 256: [0,4096) conv, [4096,7168) w_qkv^T, [7168,8192) w_proj^T
__global__ __launch_bounds__(256) void prep_kernel(
    const float* __restrict__ x, const float* __restrict__ w_qkv,
    const float* __restrict__ w_proj, unsigned short* __restrict__ Xb,
    unsigned short* __restrict__ WTq, unsigned short* __restrict__ WTp)
{
  const int bid = blockIdx.x;
  const int tid = threadIdx.x;
  if (bid < 4096) {                          // x fp32 -> bf16, 4 elts/thread
    const int i = (bid * 256 + tid) * 4;
    float4 f = *(const float4*)(x + i);
    ushort4 o;
    o.x = f2bf(f.x); o.y = f2bf(f.y); o.z = f2bf(f.z); o.w = f2bf(f.w);
    *(ushort4*)(Xb + i) = o;
  } else {                                   // fp32 [K][N] -> bf16 [N][K]
    __shared__ float tile[32][33];
    const float* in; unsigned short* out; int N, bx, by;
    if (bid < 7168) { const int b2 = bid - 4096; in = w_qkv;  out = WTq; N = 3072; bx = b2 % 96; by = b2 / 96; }
    else            { const int b3 = bid - 7168; in = w_proj; out = WTp; N = 1024; bx = b3 & 31; by = b3 >> 5; }
    const int tx = tid & 31, ty = tid >> 5;  // 32 x 8
    const int n0 = bx * 32, k0 = by * 32;
#pragma unroll
    for (int i = ty; i < 32; i += 8)
      tile[i][tx] = in[(size_t)(k0 + i) * N + (n0 + tx)];
    __syncthreads();
#pragma unroll
    for (int i = ty; i < 32; i += 8)
      out[(size_t)(n0 + i) * 1024 + (k0 + tx)] = f2bf(tile[tx][i]);
  }
}

// ---------------- basic GEMM mainloop (R0-proven, used by proj) ----------
template <int MI, int NI>
__device__ __forceinline__ void gemm_mainloop(
    const unsigned short* __restrict__ A,   // [M][K] row-major bf16
    const unsigned short* __restrict__ BT,  // [N][K] row-major bf16
    int K, int mBlk, int nBlk,
    unsigned short* As, unsigned short* Bs,
    f32x4 (&acc)[MI][NI], int lane, int wave)
{
  const int l16 = lane & 15, quad = lane >> 4;
  const int mW = (wave >> 1) * MI * 16;
  const int nW = (wave & 1) * NI * 16;
  constexpr int AROWS = 2 * MI * 16;
  constexpr int BROWS = 2 * NI * 16;
  constexpr int AINST = AROWS / 64;
  constexpr int BINST = BROWS / 64;
  const int rl = lane >> 2;           // 16 rows per instruction
  const int cl = (lane & 3) * 8;      // 4 lanes cover one 32-elem row

  for (int k0 = 0; k0 < K; k0 += 32) {
    __syncthreads();
#pragma unroll
    for (int t = 0; t < AINST; ++t) {
      const int rbase = wave * (AROWS / 4) + t * 16;
      async_load16(A + (size_t)(mBlk + rbase + rl) * K + k0 + cl, &As[rbase * 32]);
    }
#pragma unroll
    for (int t = 0; t < BINST; ++t) {
      const int rbase = wave * (BROWS / 4) + t * 16;
      async_load16(BT + (size_t)(nBlk + rbase + rl) * K + k0 + cl, &Bs[rbase * 32]);
    }
    __syncthreads();

    bf16x8 af[MI], bf[NI];
#pragma unroll
    for (int i = 0; i < MI; ++i)
      af[i] = *(const bf16x8*)&As[(mW + i * 16 + l16) * 32 + quad * 8];
#pragma unroll
    for (int j = 0; j < NI; ++j)
      bf[j] = *(const bf16x8*)&Bs[(nW + j * 16 + l16) * 32 + quad * 8];
#pragma unroll
    for (int i = 0; i < MI; ++i)
#pragma unroll
      for (int j = 0; j < NI; ++j)
        acc[i][j] = __builtin_amdgcn_mfma_f32_16x16x32_bf16(af[i], bf[j], acc[i][j], 0, 0, 0);
  }
}

// ---------------- QKV GEMM: 256x256, 2 barriers per K-tile ---------------
// Q plane: [2][16][2048][64] pre-scaled by 0.125*log2(e)
// K plane: [2][16][2048][64]
// V plane: TRANSPOSED [2][16][64][2048]
__global__ __launch_bounds__(512, 2) void qkv_gemm_kernel(
    const unsigned short* __restrict__ A,   // x bf16 [4096][1024]
    const unsigned short* __restrict__ WT,  // w_qkv^T bf16 [3072][1024]
    const float* __restrict__ bias,         // [3072]
    unsigned short* __restrict__ QKV)
{
  __shared__ __align__(16) unsigned short Al[2][2][256][32];  // 64 KB
  __shared__ __align__(16) unsigned short Bl[2][2][256][32];  // 64 KB
  const int lane = threadIdx.x & 63;
  const int wave = threadIdx.x >> 6;       // 0..7
  const int l16 = lane & 15, quad = lane >> 4;
  const int wm = wave >> 2, wn = wave & 3; // 2 x 4 wave grid

  // XCD map: 192 blocks; XCD x owns a 4bx x 6by rectangle (bijective).
  const int bid = blockIdx.x;
  const int xcd = bid & 7, rb = bid >> 3;            // rb in [0,24)
  const int bx = (xcd & 3) * 4 + (rb & 3);           // [0,16)
  const int by = (xcd >> 2) * 6 + (rb >> 2);         // [0,12)
  const int mBlk = bx * 256, nBlk = by * 256;

  const int srow = wave * 32 + (lane >> 2);  // staging row (16 rows/instr)
  const int scol = lane & 3;                 // 16B slot within 64B row

  // stage one kh sub-tile's per-wave share (2 instr, 32 rows):
  // LDS dest linear; global source pre-swizzled by c^=(row>>1)&3 (rule 21).
  auto stage = [&](const unsigned short* __restrict__ G, int gRow0,
                   unsigned short (*L)[32], int kOff) {
#pragma unroll
    for (int i = 0; i < 2; ++i) {
      const int row = srow + i * 16;
      const int c = scol ^ ((row >> 1) & 3);
      async_load16(G + (size_t)(gRow0 + row) * 1024 + kOff + c * 8,
                   &L[wave * 32 + i * 16][0]);
    }
  };

  auto rdA = [&](int buf, int kh, int mi) -> bf16x8 {
    const int r = wm * 128 + mi * 16 + l16;
    return *(const bf16x8*)&Al[buf][kh][r][(quad ^ ((r >> 1) & 3)) * 8];
  };
  auto rdB = [&](int buf, int kh, int n) -> bf16x8 {
    const int r = wn * 64 + n * 16 + l16;
    return *(const bf16x8*)&Bl[buf][kh][r][(quad ^ ((r >> 1) & 3)) * 8];
  };

  f32x4 acc[8][4];
  const f32x4 z4 = {0.f, 0.f, 0.f, 0.f};
#pragma unroll
  for (int i = 0; i < 8; ++i)
#pragma unroll
    for (int j = 0; j < 4; ++j) acc[i][j] = z4;

  // prologue: tile 0 -> buf 0; gate kh0, leave kh1 (4 loads) in flight.
  stage(A, mBlk, Al[0][0], 0);
  stage(WT, nBlk, Bl[0][0], 0);
  stage(A, mBlk, Al[0][1], 32);
  stage(WT, nBlk, Bl[0][1], 32);
  asm volatile("s_waitcnt vmcnt(4)\n\ts_barrier" ::: "memory");

  for (int t = 0; t < 16; ++t) {
    const int cur = t & 1, nxt = cur ^ 1;
    const int tn = (t + 1 < 16) ? t + 1 : 15;   // dummy re-stage on last tile
    const int kO = tn * 64;
    bf16x8 bfr[4], afr[8];

    // ---- half A (kh0): stage kh0(t+1); 12 ds_read; 32 MFMA;
    //      vmcnt(4) retires kh1(t) (read next half), leaves kh0(t+1); bar
    stage(A, mBlk, Al[nxt][0], kO);
    stage(WT, nBlk, Bl[nxt][0], kO);
#pragma unroll
    for (int n = 0; n < 4; ++n) bfr[n] = rdB(cur, 0, n);
#pragma unroll
    for (int i = 0; i < 8; ++i) afr[i] = rdA(cur, 0, i);
    __builtin_amdgcn_s_setprio(1);
#pragma unroll
    for (int i = 0; i < 8; ++i)
#pragma unroll
      for (int n = 0; n < 4; ++n)
        acc[i][n] = __builtin_amdgcn_mfma_f32_16x16x32_bf16(afr[i], bfr[n], acc[i][n], 0, 0, 0);
    __builtin_amdgcn_s_setprio(0);
    asm volatile("s_waitcnt vmcnt(4)\n\ts_barrier" ::: "memory");

    // ---- half B (kh1): stage kh1(t+1); 12 ds_read; 32 MFMA;
    //      vmcnt(4) retires kh0(t+1) (read by next tile), leaves kh1(t+1); bar
    stage(A, mBlk, Al[nxt][1], kO + 32);
    stage(WT, nBlk, Bl[nxt][1], kO + 32);
#pragma unroll
    for (int n = 0; n < 4; ++n) bfr[n] = rdB(cur, 1, n);
#pragma unroll
    for (int i = 0; i < 8; ++i) afr[i] = rdA(cur, 1, i);
    __builtin_amdgcn_s_setprio(1);
#pragma unroll
    for (int i = 0; i < 8; ++i)
#pragma unroll
      for (int n = 0; n < 4; ++n)
        acc[i][n] = __builtin_amdgcn_mfma_f32_16x16x32_bf16(afr[i], bfr[n], acc[i][n], 0, 0, 0);
    __builtin_amdgcn_s_setprio(0);
    asm volatile("s_waitcnt vmcnt(4)\n\ts_barrier" ::: "memory");
  }
  asm volatile("s_waitcnt vmcnt(0)" ::: "memory");  // drain dummy stages

  // ---- epilogue (per wave: 128 x 64 at m0,n0) ----
  const int m0 = mBlk + wm * 128;
  const int n0 = nBlk + wn * 64;
  const int whichW = n0 >> 10;          // uniform per wave (64-aligned)
  const int bb = m0 >> 11;              // uniform per wave (128-aligned)
  const int sBase = (m0 & 2047);
  const size_t planeE = (size_t)2 * 16 * 2048 * 64;

  if (whichW == 2) {                    // V -> transposed store
    unsigned short* Vb = QKV + 2 * planeE;
#pragma unroll
    for (int j = 0; j < 4; ++j) {
      const int rem = (n0 & 1023) + j * 16 + l16;
      const int hh = rem >> 6, hd = rem & 63;
      const float bv = bias[n0 + j * 16 + l16];
      unsigned short* col = Vb + (((size_t)bb * 16 + hh) * 64 + hd) * 2048;
#pragma unroll
      for (int i = 0; i < 8; ++i) {
        unsigned short pk[4];
#pragma unroll
        for (int r = 0; r < 4; ++r) pk[r] = f2bf(acc[i][j][r] + bv);
        *(ushort4*)&col[sBase + i * 16 + quad * 4] = *(ushort4*)pk;
      }
    }
  } else {
    // Q: fold 1/sqrt(Hd) AND log2(e) -> scores come out in log2 domain
    const float scale = (whichW == 0) ? 0.18033688011112042f : 1.0f;
#pragma unroll
    for (int j = 0; j < 4; ++j) {
      const int n = n0 + j * 16 + l16;
      const float bv = bias[n];
      const int rem = n & 1023;
      const int hh = rem >> 6, hd = rem & 63;
      unsigned short* pl = QKV + (size_t)whichW * planeE +
                           (((size_t)bb * 16 + hh) * 2048) * 64 + hd;
#pragma unroll
      for (int r = 0; r < 4; ++r) {
        const int s = sBase + (quad * 4 + r);
#pragma unroll
        for (int i = 0; i < 8; ++i)
          pl[(size_t)(s + i * 16) * 64] = f2bf((acc[i][j][r] + bv) * scale);
      }
    }
  }
}

// ---------------- flash attention (swapped 32x32, in-register P) ----------
// Block = 4 waves x 32 queries = 128 queries of one (b,h). Linear grid 512:
//   xcd = lin&7, slot = lin>>3; col = xcd*4 + (slot>>4); b = col>>4, h = col&15
//   qg = slot<32 ? slot&15 : 15-(slot&15)
// -> each XCD sees only 4 (b,h) columns (2MB K/V, L2-resident); CU c within
// an XCD gets slots c and c+32 -> qg complement pair (balanced work).
// Body is the R1-proven schedule: per tile QK -> softmax -> PV, 3 buffers.
__global__ __launch_bounds__(256, 2) void attn_kernel(
    const unsigned short* __restrict__ QKV,
    unsigned short* __restrict__ AO)         // [2][2048][1024] bf16
{
  __shared__ __align__(16) unsigned short Ks[3 * 64 * 64];  // 24 KB
  __shared__ __align__(16) unsigned short Vs[3 * 64 * 64];  // 24 KB
  const int lane = threadIdx.x & 63;
  const int wave = threadIdx.x >> 6;
  const int l31 = lane & 31;
  const int hi  = lane >> 5;

  const int lin  = blockIdx.x;
  const int xcd  = lin & 7;
  const int slot = lin >> 3;                 // 0..63
  const int col  = xcd * 4 + (slot >> 4);    // 0..31
  const int b = col >> 4, h = col & 15;
  const int qg = (slot < 32) ? (slot & 15) : (15 - (slot & 15));
  const int qw = qg * 128 + wave * 32;       // this wave's first query

  const size_t planeE = (size_t)2 * 16 * 2048 * 64;
  const size_t bhS = ((size_t)b * 16 + h) * (size_t)(2048 * 64);
  const unsigned short* Q   = QKV + bhS;                 // [2048][64], pre-scaled
  const unsigned short* Kg  = QKV + planeE + bhS;        // [2048][64]
  const unsigned short* VTg = QKV + 2 * planeE + bhS;    // [64][2048]

  // Q B-frags: B[k=hd][n=query=l31]; frag t covers hd t*16 + hi*8 .. +7
  bf16x8 qf_[4];
#pragma unroll
  for (int t = 0; t < 4; ++t)
    qf_[t] = *(const bf16x8*)(Q + (size_t)(qw + l31) * 64 + t * 16 + hi * 8);

  bf16x8 onesf;                               // B-frag of bf16(1.0)
#pragma unroll
  for (int i = 0; i < 8; ++i) onesf[i] = (short)0x3F80;

  f32x16 O[2], Osum;
#pragma unroll
  for (int r = 0; r < 16; ++r) { O[0][r] = 0.f; O[1][r] = 0.f; Osum[r] = 0.f; }

  // DMA role: waves 0,1 stage K; waves 2,3 stage V. 4 instr/wave, 1KB each.
  const int tbase = (wave & 1) * 4;
  const bool doV = wave >= 2;

  auto stage = [&](int tileIdx, int bufIdx) {
    const int kt = tileIdx * 64;
    unsigned short* Kb = Ks + bufIdx * 4096;
    unsigned short* Vb = Vs + bufIdx * 4096;
#pragma unroll
    for (int i = 0; i < 4; ++i) {
      const int t = tbase + i;
      const int s = t * 64 + lane;           // 16B slot this lane fills
      const int row = s >> 3;
      const int c = (s & 7) ^ (row & 7);     // un-swizzle: which global 16B
      if (doV)
        async_load16(VTg + (size_t)row * 2048 + kt + c * 8, Vb + t * 512);
      else
        async_load16(Kg + (size_t)(kt + row) * 64 + c * 8, Kb + t * 512);
    }
  };

  const int nt = qg * 2 + 2;                 // staged tiles (covers wave 3)
  stage(0, 0);
  stage(1, 1);
  for (int ti = 0; ti < nt; ++ti) {
    // wait for stage(ti) (leaves the 4 newest = stage(ti+1) in flight),
    // then barrier. NO vmcnt(0) drain — the AITER-style pipeline.
    asm volatile("s_waitcnt vmcnt(4)\n\ts_barrier" ::: "memory");
    const int tn = (ti + 2 < nt) ? ti + 2 : nt - 1;  // dummy re-stage at the end
    stage(tn, (ti + 2) % 3);                 // keeps 4 in flight per wave, always
    const int kt = ti * 64;
    const unsigned short* Kb = Ks + (ti % 3) * 4096;
    const unsigned short* Vb = Vs + (ti % 3) * 4096;

    if (kt <= qw + 31) {
      const bool dmask = (kt + 63 > qw);
#pragma unroll
      for (int kg = 0; kg < 2; ++kg) {
        // K A-frags: A[m=key=l31(+kg*32)][k=hd chunk], swizzled LDS
        const int krow = kg * 32 + l31;
        const int ks7 = krow & 7;
        bf16x8 ka[4];
#pragma unroll
        for (int t = 0; t < 4; ++t)
          ka[t] = *(const bf16x8*)&Kb[(krow * 8 + ((t * 2 + hi) ^ ks7)) * 8];

        f32x16 sc;
#pragma unroll
        for (int r = 0; r < 16; ++r) sc[r] = 0.f;
        __builtin_amdgcn_s_setprio(1);
#pragma unroll
        for (int t = 0; t < 4; ++t)
          sc = __builtin_amdgcn_mfma_f32_32x32x16_bf16(ka[t], qf_[t], sc, 0, 0, 0);
        __builtin_amdgcn_s_setprio(0);

        // softmax term, fully in-register
        float p[16];
#pragma unroll
        for (int r = 0; r < 16; ++r) {
          float v = sc[r];
          if (dmask) {
            const int key = kt + kg * 32 + (r & 3) + 8 * (r >> 2) + 4 * hi;
            if (key > qw + l31) v = -INFINITY;
          }
          p[r] = EXP2(v);                    // native v_exp_f32
        }
        // pack pairs (keys ascend 2-at-a-time within each lane half)
        unsigned c8[8];
#pragma unroll
        for (int i = 0; i < 8; ++i)
          asm("v_cvt_pk_bf16_f32 %0, %1, %2"
              : "=v"(c8[i]) : "v"(p[2 * i]), "v"(p[2 * i + 1]));

#pragma unroll
        for (int half = 0; half < 2; ++half) {
          // assemble PV A-frag for 16-key chunk kc = kg*2+half:
          // lane half 0 needs keys kc*16+0..7, half 1 needs +8..15.
          unsigned a0 = c8[4 * half + 0], a1 = c8[4 * half + 1];
          unsigned a2 = c8[4 * half + 2], a3 = c8[4 * half + 3];
          asm("v_permlane32_swap_b32 %0, %1" : "+v"(a0), "+v"(a2));
          asm("v_permlane32_swap_b32 %0, %1" : "+v"(a1), "+v"(a3));
          union { unsigned u[4]; bf16x8 v; } pa;
          pa.u[0] = a0; pa.u[1] = a1; pa.u[2] = a2; pa.u[3] = a3;
          const int kc = kg * 2 + half;

          __builtin_amdgcn_s_setprio(1);
          // row-sum on the matrix pipe; lands in O's row layout
          Osum = __builtin_amdgcn_mfma_f32_32x32x16_bf16(pa.v, onesf, Osum, 0, 0, 0);
#pragma unroll
          for (int g = 0; g < 2; ++g) {
            const int vrow = g * 32 + l31;   // hd row of V^T
            bf16x8 vb = *(const bf16x8*)&Vb[(vrow * 8 + ((kc * 2 + hi) ^ (vrow & 7))) * 8];
            O[g] = __builtin_amdgcn_mfma_f32_32x32x16_bf16(pa.v, vb, O[g], 0, 0, 0);
          }
          __builtin_amdgcn_s_setprio(0);
        }
      }
    }
  }

  // epilogue: normalize by Osum (already per-row, replicated across lanes)
  unsigned short* base = AO + ((size_t)b * 2048 + qw) * 1024 + h * 64 + l31;
#pragma unroll
  for (int r = 0; r < 16; ++r) {
    const float inv = 1.0f / Osum[r];
    const int row = (r & 3) + 8 * (r >> 2) + 4 * hi;
#pragma unroll
    for (int g = 0; g < 2; ++g)
      base[(size_t)row * 1024 + g * 32] = f2bf(O[g][r] * inv);
  }
}

// ---------------- proj GEMM: [4096,1024]x[1024,1024] + bias -> fp32 out ----------------
// 64x128 block tile -> grid 64x8 = 512 blocks (2/CU)
__global__ __launch_bounds__(256) void proj_gemm_kernel(
    const unsigned short* __restrict__ A,   // AO bf16 [4096][1024]
    const unsigned short* __restrict__ WT,  // w_proj^T bf16 [1024][1024]
    const float* __restrict__ bias,         // [1024]
    float* __restrict__ out)                // [4096][1024] fp32
{
  __shared__ unsigned short As[64 * 32];
  __shared__ unsigned short Bs[128 * 32];
  const int lane = threadIdx.x & 63;
  const int wave = threadIdx.x >> 6;
  const int l16 = lane & 15, quad = lane >> 4;

  f32x4 acc[2][4];
  const f32x4 z4 = {0.f, 0.f, 0.f, 0.f};
#pragma unroll
  for (int i = 0; i < 2; ++i)
#pragma unroll
    for (int j = 0; j < 4; ++j) acc[i][j] = z4;

  gemm_mainloop<2, 4>(A, WT, 1024, blockIdx.x * 64, blockIdx.y * 128,
                      As, Bs, acc, lane, wave);

  const int m0 = blockIdx.x * 64 + (wave >> 1) * 32;
  const int n0 = blockIdx.y * 128 + (wave & 1) * 64;
#pragma unroll
  for (int i = 0; i < 2; ++i) {
#pragma unroll
    for (int j = 0; j < 4; ++j) {
      const int n = n0 + j * 16 + l16;
      const float bv = bias[n];
#pragma unroll
      for (int r = 0; r < 4; ++r) {
        const int m = m0 + i * 16 + quad * 4 + r;
        out[(size_t)m * 1024 + n] = acc[i][j][r] + bv;
      }
    }
  }
}

extern "C" void kernel_launch(void* const* d_in, const int* in_sizes, int n_in,
                              void* d_out, int out_size, void* d_ws, size_t ws_size,
                              hipStream_t stream) {
  const float* x      = (const float*)d_in[0];  // [2,2048,1024]
  const float* w_qkv  = (const float*)d_in[1];  // [1024,3072]
  const float* b_qkv  = (const float*)d_in[2];  // [3072]
  const float* w_proj = (const float*)d_in[3];  // [1024,1024]
  const float* b_proj = (const float*)d_in[4];  // [1024]
  float* out = (float*)d_out;                   // [2,2048,1024] fp32

  // workspace layout (ushort elems): Xb 4M | WTq 3M | WTp 1M | QKV 12M | AO 4M = 48 MiB
  unsigned short* Xb  = (unsigned short*)d_ws;
  unsigned short* WTq = Xb + (size_t)4096 * 1024;
  unsigned short* WTp = WTq + (size_t)3072 * 1024;
  unsigned short* QKV = WTp + (size_t)1024 * 1024;
  unsigned short* AO  = QKV + (size_t)3 * 4096 * 1024;

  prep_kernel<<<8192, 256, 0, stream>>>(x, w_qkv, w_proj, Xb, WTq, WTp);
  qkv_gemm_kernel<<<192, 512, 0, stream>>>(Xb, WTq, b_qkv, QKV);
  attn_kernel<<<512, 256, 0, stream>>>(QKV, AO);
  proj_gemm_kernel<<<dim3(64, 8), 256, 0, stream>>>(AO, WTp, b_proj, out);
}